// Round 1
// baseline (1028.993 us; speedup 1.0000x reference)
//
#include <hip/hip_runtime.h>

#define N_NODES 100000
#define N_EDGES 1600000
#define ETOT    1700000   // edges + self loops
#define IN_CH   128
#define C1      256       // HEADS*HID
#define HID     64
#define BN_EPS  1e-5f
#define SLOPE   0.2f
#define NCHUNK  98        // ceil(N/1024)

__device__ __forceinline__ float leaky(float x) { return x > 0.f ? x : SLOPE * x; }
__device__ __forceinline__ float elu_f(float x) { return x > 0.f ? x : expf(x) - 1.f; }

// ---------------- CSR build ----------------
__global__ void __launch_bounds__(256) k_init_deg(int* __restrict__ deg) {
  int n = blockIdx.x * 256 + threadIdx.x;
  if (n < N_NODES) deg[n] = 1;  // self loop
}

__global__ void __launch_bounds__(256) k_deg(const int* __restrict__ edge, int* __restrict__ deg) {
  int i = blockIdx.x * 256 + threadIdx.x;
  if (i < N_EDGES) atomicAdd(&deg[edge[N_EDGES + i]], 1);
}

__global__ void __launch_bounds__(256) k_scan_part(const int* __restrict__ deg, int* __restrict__ part) {
  __shared__ int ls[256];
  int t = threadIdx.x;
  int base = blockIdx.x * 1024 + t * 4;
  int s = 0;
#pragma unroll
  for (int j = 0; j < 4; j++) if (base + j < N_NODES) s += deg[base + j];
  ls[t] = s;
  __syncthreads();
  for (int off = 128; off >= 1; off >>= 1) {
    if (t < off) ls[t] += ls[t + off];
    __syncthreads();
  }
  if (t == 0) part[blockIdx.x] = ls[0];
}

__global__ void k_scan_top(int* __restrict__ part, int* __restrict__ row_ptr) {
  if (threadIdx.x == 0 && blockIdx.x == 0) {
    int run = 0;
    for (int i = 0; i < NCHUNK; i++) { int t = part[i]; part[i] = run; run += t; }
    row_ptr[N_NODES] = run;   // == ETOT
  }
}

__global__ void __launch_bounds__(256) k_scan_down(const int* __restrict__ deg, const int* __restrict__ part,
                                                   int* __restrict__ row_ptr, int* __restrict__ cursor) {
  __shared__ int ls[256];
  int t = threadIdx.x;
  int base = blockIdx.x * 1024 + t * 4;
  int v[4];
#pragma unroll
  for (int j = 0; j < 4; j++) v[j] = (base + j < N_NODES) ? deg[base + j] : 0;
  int tsum = v[0] + v[1] + v[2] + v[3];
  ls[t] = tsum;
  __syncthreads();
  for (int off = 1; off < 256; off <<= 1) {
    int add = (t >= off) ? ls[t - off] : 0;
    __syncthreads();
    ls[t] += add;
    __syncthreads();
  }
  int excl = ls[t] - tsum + part[blockIdx.x];
#pragma unroll
  for (int j = 0; j < 4; j++) {
    int idx = base + j;
    if (idx < N_NODES) { row_ptr[idx] = excl; cursor[idx] = excl; }
    excl += v[j];
  }
}

__global__ void __launch_bounds__(256) k_fill(const int* __restrict__ edge, int* __restrict__ cursor,
                                              int* __restrict__ col) {
  int i = blockIdx.x * 256 + threadIdx.x;
  int s, d;
  if (i < N_EDGES) { s = edge[i]; d = edge[N_EDGES + i]; }
  else if (i < ETOT) { s = i - N_EDGES; d = s; }
  else return;
  int pos = atomicAdd(&cursor[d], 1);
  col[pos] = s;
}

// ---------------- GEMM1: h1 = x @ W1  [N,128]x[128,256], fused att dots ----------------
__global__ void __launch_bounds__(256) k_gemm1(const float* __restrict__ x, const float* __restrict__ W1,
                                               const float* __restrict__ attS, const float* __restrict__ attD,
                                               float* __restrict__ h1, float* __restrict__ aS,
                                               float* __restrict__ aD) {
  __shared__ float xs[64][128];
  int tid = threadIdx.x;
  int colg = tid & 63;       // 64 col groups of 4 cols
  int rowg = tid >> 6;       // 4 row groups of 16 rows
  int row0 = blockIdx.x * 64;
  // stage x tile (64x128 f32 = 32KB), contiguous
#pragma unroll
  for (int i = 0; i < 8; i++) {
    int idx = tid + i * 256;           // float4 index, 2048 total
    int r = idx >> 5;                  // 32 float4 per row
    int k4 = idx & 31;
    int gr = row0 + r; if (gr >= N_NODES) gr = N_NODES - 1;
    ((float4*)xs)[idx] = ((const float4*)(x + (size_t)gr * IN_CH))[k4];
  }
  __syncthreads();
  float acc[16][4] = {};
  int j0 = colg * 4;
  for (int k = 0; k < IN_CH; k += 4) {
    float4 w0 = *(const float4*)(W1 + (size_t)(k + 0) * C1 + j0);
    float4 w1 = *(const float4*)(W1 + (size_t)(k + 1) * C1 + j0);
    float4 w2 = *(const float4*)(W1 + (size_t)(k + 2) * C1 + j0);
    float4 w3 = *(const float4*)(W1 + (size_t)(k + 3) * C1 + j0);
#pragma unroll
    for (int r = 0; r < 16; r++) {
      float4 xv = *(const float4*)(&xs[rowg * 16 + r][k]);
      acc[r][0] += xv.x * w0.x + xv.y * w1.x + xv.z * w2.x + xv.w * w3.x;
      acc[r][1] += xv.x * w0.y + xv.y * w1.y + xv.z * w2.y + xv.w * w3.y;
      acc[r][2] += xv.x * w0.z + xv.y * w1.z + xv.z * w2.z + xv.w * w3.z;
      acc[r][3] += xv.x * w0.w + xv.y * w1.w + xv.z * w2.w + xv.w * w3.w;
    }
  }
  int head = colg >> 4;
  int cc = (colg & 15) * 4;
  float4 as4 = *(const float4*)(attS + head * HID + cc);
  float4 ad4 = *(const float4*)(attD + head * HID + cc);
#pragma unroll
  for (int r = 0; r < 16; r++) {
    int gr = row0 + rowg * 16 + r;
    if (gr < N_NODES) *(float4*)(h1 + (size_t)gr * C1 + j0) = *(float4*)acc[r];
    float s = acc[r][0] * as4.x + acc[r][1] * as4.y + acc[r][2] * as4.z + acc[r][3] * as4.w;
    float d = acc[r][0] * ad4.x + acc[r][1] * ad4.y + acc[r][2] * ad4.z + acc[r][3] * ad4.w;
#pragma unroll
    for (int m = 1; m <= 8; m <<= 1) { s += __shfl_xor(s, m, 64); d += __shfl_xor(d, m, 64); }
    if ((colg & 15) == 0 && gr < N_NODES) {
      aS[(size_t)gr * 4 + head] = s;
      aD[(size_t)gr * 4 + head] = d;
    }
  }
}

// ---------------- layer-1 aggregate + bias + BN1 + ELU ----------------
__global__ void __launch_bounds__(256) k_agg1(const int* __restrict__ row_ptr, const int* __restrict__ col,
                                              const float* __restrict__ aS, const float* __restrict__ aD,
                                              const float* __restrict__ h1, const float* __restrict__ b1,
                                              const float* __restrict__ g1, const float* __restrict__ be1,
                                              const float* __restrict__ m1, const float* __restrict__ v1,
                                              float* __restrict__ hm) {
  int wave = threadIdx.x >> 6;
  int lane = threadIdx.x & 63;
  int d = blockIdx.x * 4 + wave;
  if (d >= N_NODES) return;
  int head = lane >> 4;
  float ad = aD[(size_t)d * 4 + head];
  int s0 = row_ptr[d], s1 = row_ptr[d + 1];
  float mx = -INFINITY;
  for (int i = s0; i < s1; i++) {
    int s = col[i];
    float e = leaky(aS[(size_t)s * 4 + head] + ad);
    mx = fmaxf(mx, e);
  }
  float denom = 0.f;
  float4 acc = {0.f, 0.f, 0.f, 0.f};
  int c0 = lane * 4;
  for (int i = s0; i < s1; i++) {
    int s = col[i];
    float e = leaky(aS[(size_t)s * 4 + head] + ad);
    float w = expf(e - mx);
    denom += w;
    float4 hv = *(const float4*)(h1 + (size_t)s * C1 + c0);
    acc.x += w * hv.x; acc.y += w * hv.y; acc.z += w * hv.z; acc.w += w * hv.w;
  }
  float inv = 1.f / (denom + 1e-16f);
  float4 bb = *(const float4*)(b1 + c0);
  float4 gg = *(const float4*)(g1 + c0);
  float4 be = *(const float4*)(be1 + c0);
  float4 mm = *(const float4*)(m1 + c0);
  float4 vv = *(const float4*)(v1 + c0);
  float4 o;
  o.x = elu_f((acc.x * inv + bb.x - mm.x) * rsqrtf(vv.x + BN_EPS) * gg.x + be.x);
  o.y = elu_f((acc.y * inv + bb.y - mm.y) * rsqrtf(vv.y + BN_EPS) * gg.y + be.y);
  o.z = elu_f((acc.z * inv + bb.z - mm.z) * rsqrtf(vv.z + BN_EPS) * gg.z + be.z);
  o.w = elu_f((acc.w * inv + bb.w - mm.w) * rsqrtf(vv.w + BN_EPS) * gg.w + be.w);
  *(float4*)(hm + (size_t)d * C1 + c0) = o;
}

// ---------------- GEMM2: h2 = hm @ W2  [N,256]x[256,64], fused att dots ----------------
__global__ void __launch_bounds__(256) k_gemm2(const float* __restrict__ hm, const float* __restrict__ W2,
                                               const float* __restrict__ attS, const float* __restrict__ attD,
                                               float* __restrict__ h2, float* __restrict__ aS,
                                               float* __restrict__ aD) {
  __shared__ float xs[64][256];    // 64 KB
  int tid = threadIdx.x;
  int colg = tid & 31;     // 32 col groups of 2 cols
  int rowg = tid >> 5;     // 8 row groups of 8 rows
  int row0 = blockIdx.x * 64;
#pragma unroll
  for (int i = 0; i < 16; i++) {
    int idx = tid + i * 256;     // float4 index, 4096 total
    int r = idx >> 6;            // 64 float4 per row
    int k4 = idx & 63;
    int gr = row0 + r; if (gr >= N_NODES) gr = N_NODES - 1;
    ((float4*)xs)[idx] = ((const float4*)(hm + (size_t)gr * C1))[k4];
  }
  __syncthreads();
  float acc[8][2] = {};
  int c0 = colg * 2;
  for (int k = 0; k < C1; k += 4) {
    float2 w0 = *(const float2*)(W2 + (size_t)(k + 0) * HID + c0);
    float2 w1 = *(const float2*)(W2 + (size_t)(k + 1) * HID + c0);
    float2 w2 = *(const float2*)(W2 + (size_t)(k + 2) * HID + c0);
    float2 w3 = *(const float2*)(W2 + (size_t)(k + 3) * HID + c0);
#pragma unroll
    for (int r = 0; r < 8; r++) {
      float4 xv = *(const float4*)(&xs[rowg * 8 + r][k]);
      acc[r][0] += xv.x * w0.x + xv.y * w1.x + xv.z * w2.x + xv.w * w3.x;
      acc[r][1] += xv.x * w0.y + xv.y * w1.y + xv.z * w2.y + xv.w * w3.y;
    }
  }
  float2 as2 = *(const float2*)(attS + c0);
  float2 ad2 = *(const float2*)(attD + c0);
#pragma unroll
  for (int r = 0; r < 8; r++) {
    int gr = row0 + rowg * 8 + r;
    if (gr < N_NODES) *(float2*)(h2 + (size_t)gr * HID + c0) = make_float2(acc[r][0], acc[r][1]);
    float s = acc[r][0] * as2.x + acc[r][1] * as2.y;
    float d = acc[r][0] * ad2.x + acc[r][1] * ad2.y;
#pragma unroll
    for (int m = 1; m <= 16; m <<= 1) { s += __shfl_xor(s, m, 64); d += __shfl_xor(d, m, 64); }
    if (colg == 0 && gr < N_NODES) { aS[gr] = s; aD[gr] = d; }
  }
}

// ---------------- layer-2 aggregate + bias + BN2 + ELU -> node_emb ----------------
__global__ void __launch_bounds__(256) k_agg2(const int* __restrict__ row_ptr, const int* __restrict__ col,
                                              const float* __restrict__ aS, const float* __restrict__ aD,
                                              const float* __restrict__ h2, const float* __restrict__ b2,
                                              const float* __restrict__ g2, const float* __restrict__ be2,
                                              const float* __restrict__ m2, const float* __restrict__ v2,
                                              float* __restrict__ emb) {
  int wave = threadIdx.x >> 6;
  int lane = threadIdx.x & 63;
  int d = blockIdx.x * 4 + wave;
  if (d >= N_NODES) return;
  float ad = aD[d];
  int s0 = row_ptr[d], s1 = row_ptr[d + 1];
  float mx = -INFINITY;
  for (int i = s0; i < s1; i++) {
    float e = leaky(aS[col[i]] + ad);
    mx = fmaxf(mx, e);
  }
  float denom = 0.f, acc = 0.f;
  for (int i = s0; i < s1; i++) {
    int s = col[i];
    float e = leaky(aS[s] + ad);
    float w = expf(e - mx);
    denom += w;
    acc += w * h2[(size_t)s * HID + lane];
  }
  float o = acc / (denom + 1e-16f) + b2[lane];
  o = (o - m2[lane]) * rsqrtf(v2[lane] + BN_EPS) * g2[lane] + be2[lane];
  emb[(size_t)d * HID + lane] = elu_f(o);
}

// ---------------- pooling partials ----------------
__global__ void __launch_bounds__(256) k_pool(const float* __restrict__ emb, float* __restrict__ psum,
                                              float* __restrict__ pmax) {
  __shared__ float ss[4][64], sm[4][64];
  int t = threadIdx.x;
  int c = t & 63, rg = t >> 6;
  float s = 0.f, m = -INFINITY;
  for (int n = blockIdx.x * 4 + rg; n < N_NODES; n += gridDim.x * 4) {
    float v = emb[(size_t)n * HID + c];
    s += v; m = fmaxf(m, v);
  }
  ss[rg][c] = s; sm[rg][c] = m;
  __syncthreads();
  if (t < 64) {
    psum[blockIdx.x * 64 + t] = ss[0][t] + ss[1][t] + ss[2][t] + ss[3][t];
    pmax[blockIdx.x * 64 + t] = fmaxf(fmaxf(sm[0][t], sm[1][t]), fmaxf(sm[2][t], sm[3][t]));
  }
}

// ---------------- final reduce + classifier ----------------
__global__ void __launch_bounds__(256) k_final(const float* __restrict__ psum, const float* __restrict__ pmax,
                                               const float* __restrict__ emb, const int* __restrict__ rootp,
                                               const float* __restrict__ cg1w, const float* __restrict__ cg1b,
                                               const float* __restrict__ cbng, const float* __restrict__ cbnb,
                                               const float* __restrict__ cbnm, const float* __restrict__ cbnv,
                                               const float* __restrict__ cg2w, const float* __restrict__ cg2b,
                                               const float* __restrict__ cg3w, const float* __restrict__ cg3b,
                                               float* __restrict__ out) {
  __shared__ float ss[4][64], sm[4][64];
  __shared__ float g[192], t1[64], t2[32];
  int t = threadIdx.x;
  int c = t & 63, q = t >> 6;
  float s = 0.f, m = -INFINITY;
  for (int b = q; b < 256; b += 4) {
    s += psum[b * 64 + c];
    m = fmaxf(m, pmax[b * 64 + c]);
  }
  ss[q][c] = s; sm[q][c] = m;
  __syncthreads();
  if (t < 64) {
    float tot = ss[0][t] + ss[1][t] + ss[2][t] + ss[3][t];
    float mx = fmaxf(fmaxf(sm[0][t], sm[1][t]), fmaxf(sm[2][t], sm[3][t]));
    int root = rootp[0];
    if (root > N_NODES - 1) root = N_NODES - 1;
    if (root < 0) root = 0;
    g[t] = tot / (float)N_NODES;
    g[64 + t] = mx;
    g[128 + t] = emb[(size_t)root * HID + t];
  }
  __syncthreads();
  if (t < 64) {
    float o = cg1b[t];
    for (int i = 0; i < 192; i++) o += g[i] * cg1w[i * 64 + t];
    o = (o - cbnm[t]) * rsqrtf(cbnv[t] + BN_EPS) * cbng[t] + cbnb[t];
    t1[t] = o > 0.f ? o : 0.f;
  }
  __syncthreads();
  if (t < 32) {
    float o = cg2b[t];
    for (int i = 0; i < 64; i++) o += t1[i] * cg2w[i * 32 + t];
    t2[t] = o > 0.f ? o : 0.f;
  }
  __syncthreads();
  if (t == 0) {
    float o = cg3b[0];
    for (int i = 0; i < 32; i++) o += t2[i] * cg3w[i];
    out[0] = o;
  }
}

extern "C" void kernel_launch(void* const* d_in, const int* in_sizes, int n_in,
                              void* d_out, int out_size, void* d_ws, size_t ws_size,
                              hipStream_t stream) {
  const float* x     = (const float*)d_in[0];
  const int*   edge  = (const int*)d_in[1];
  const int*   root  = (const int*)d_in[2];
  const float* W1    = (const float*)d_in[3];
  const float* attS1 = (const float*)d_in[4];
  const float* attD1 = (const float*)d_in[5];
  const float* b1    = (const float*)d_in[6];
  const float* W2    = (const float*)d_in[7];
  const float* attS2 = (const float*)d_in[8];
  const float* attD2 = (const float*)d_in[9];
  const float* b2    = (const float*)d_in[10];
  const float* bn1g  = (const float*)d_in[11];
  const float* bn1b  = (const float*)d_in[12];
  const float* bn1m  = (const float*)d_in[13];
  const float* bn1v  = (const float*)d_in[14];
  const float* bn2g  = (const float*)d_in[15];
  const float* bn2b  = (const float*)d_in[16];
  const float* bn2m  = (const float*)d_in[17];
  const float* bn2v  = (const float*)d_in[18];
  const float* cg1w  = (const float*)d_in[19];
  const float* cg1b  = (const float*)d_in[20];
  const float* cbng  = (const float*)d_in[21];
  const float* cbnb  = (const float*)d_in[22];
  const float* cbnm  = (const float*)d_in[23];
  const float* cbnv  = (const float*)d_in[24];
  const float* cg2w  = (const float*)d_in[25];
  const float* cg2b  = (const float*)d_in[26];
  const float* cg3w  = (const float*)d_in[27];
  const float* cg3b  = (const float*)d_in[28];

  // workspace arena (element offsets, 256B aligned blocks)
  char* ws = (char*)d_ws;
  size_t off = 0;
  auto carve = [&](size_t bytes) { char* p = ws + off; off += (bytes + 255) & ~(size_t)255; return p; };
  float* h1      = (float*)carve((size_t)N_NODES * C1 * 4);   // 102.4 MB
  float* hm      = (float*)carve((size_t)N_NODES * C1 * 4);   // 102.4 MB
  float* aS1     = (float*)carve((size_t)N_NODES * 4 * 4);
  float* aD1     = (float*)carve((size_t)N_NODES * 4 * 4);
  int*   deg     = (int*)  carve((size_t)N_NODES * 4);
  int*   row_ptr = (int*)  carve((size_t)(N_NODES + 1) * 4);
  int*   cursor  = (int*)  carve((size_t)N_NODES * 4);
  int*   col     = (int*)  carve((size_t)ETOT * 4);
  int*   part    = (int*)  carve(512);
  // layer-2 buffers alias the (dead after k_agg1) h1 region
  float* h2   = h1;                                  // N*64
  float* aS2  = h1 + (size_t)N_NODES * HID;          // N
  float* aD2  = aS2 + N_NODES;
  float* emb  = aD2 + N_NODES;                       // N*64
  float* psum = emb + (size_t)N_NODES * HID;         // 256*64
  float* pmax = psum + 256 * 64;

  // CSR build
  k_init_deg<<<(N_NODES + 255) / 256, 256, 0, stream>>>(deg);
  k_deg<<<(N_EDGES + 255) / 256, 256, 0, stream>>>(edge, deg);
  k_scan_part<<<NCHUNK, 256, 0, stream>>>(deg, part);
  k_scan_top<<<1, 64, 0, stream>>>(part, row_ptr);
  k_scan_down<<<NCHUNK, 256, 0, stream>>>(deg, part, row_ptr, cursor);
  k_fill<<<(ETOT + 255) / 256, 256, 0, stream>>>(edge, cursor, col);
  // layer 1
  k_gemm1<<<(N_NODES + 63) / 64, 256, 0, stream>>>(x, W1, attS1, attD1, h1, aS1, aD1);
  k_agg1<<<(N_NODES + 3) / 4, 256, 0, stream>>>(row_ptr, col, aS1, aD1, h1, b1, bn1g, bn1b, bn1m, bn1v, hm);
  // layer 2
  k_gemm2<<<(N_NODES + 63) / 64, 256, 0, stream>>>(hm, W2, attS2, attD2, h2, aS2, aD2);
  k_agg2<<<(N_NODES + 3) / 4, 256, 0, stream>>>(row_ptr, col, aS2, aD2, h2, b2, bn2g, bn2b, bn2m, bn2v, emb);
  // pooling + classifier
  k_pool<<<256, 256, 0, stream>>>(emb, psum, pmax);
  k_final<<<1, 256, 0, stream>>>(psum, pmax, emb, root, cg1w, cg1b, cbng, cbnb, cbnm, cbnv,
                                 cg2w, cg2b, cg3w, cg3b, (float*)d_out);
}

// Round 2
// 824.585 us; speedup vs baseline: 1.2479x; 1.2479x over previous
//
#include <hip/hip_runtime.h>

#define N_NODES 100000
#define N_EDGES 1600000
#define ETOT    1700000   // edges + self loops
#define IN_CH   128
#define C1      256       // HEADS*HID
#define HID     64
#define BN_EPS  1e-5f
#define SLOPE   0.2f
#define NCHUNK  98        // ceil(N/1024)

__device__ __forceinline__ float leaky(float x) { return x > 0.f ? x : SLOPE * x; }
__device__ __forceinline__ float elu_f(float x) { return x > 0.f ? x : expf(x) - 1.f; }
__device__ __forceinline__ unsigned short f2bf(float f) {   // RNE fp32->bf16
  unsigned int b = __float_as_uint(f);
  return (unsigned short)((b + 0x7FFFu + ((b >> 16) & 1u)) >> 16);
}
__device__ __forceinline__ float bf2f(unsigned short u) {
  return __uint_as_float((unsigned int)u << 16);
}

// ---------------- CSR build ----------------
__global__ void __launch_bounds__(256) k_init_deg(int* __restrict__ deg) {
  int n = blockIdx.x * 256 + threadIdx.x;
  if (n < N_NODES) deg[n] = 1;  // self loop
}

__global__ void __launch_bounds__(256) k_deg(const int* __restrict__ edge, int* __restrict__ deg) {
  int i = blockIdx.x * 256 + threadIdx.x;
  if (i < N_EDGES) atomicAdd(&deg[edge[N_EDGES + i]], 1);
}

__global__ void __launch_bounds__(256) k_scan_part(const int* __restrict__ deg, int* __restrict__ part) {
  __shared__ int ls[256];
  int t = threadIdx.x;
  int base = blockIdx.x * 1024 + t * 4;
  int s = 0;
#pragma unroll
  for (int j = 0; j < 4; j++) if (base + j < N_NODES) s += deg[base + j];
  ls[t] = s;
  __syncthreads();
  for (int off = 128; off >= 1; off >>= 1) {
    if (t < off) ls[t] += ls[t + off];
    __syncthreads();
  }
  if (t == 0) part[blockIdx.x] = ls[0];
}

__global__ void k_scan_top(int* __restrict__ part, int* __restrict__ row_ptr) {
  if (threadIdx.x == 0 && blockIdx.x == 0) {
    int run = 0;
    for (int i = 0; i < NCHUNK; i++) { int t = part[i]; part[i] = run; run += t; }
    row_ptr[N_NODES] = run;   // == ETOT
  }
}

__global__ void __launch_bounds__(256) k_scan_down(const int* __restrict__ deg, const int* __restrict__ part,
                                                   int* __restrict__ row_ptr, int* __restrict__ cursor) {
  __shared__ int ls[256];
  int t = threadIdx.x;
  int base = blockIdx.x * 1024 + t * 4;
  int v[4];
#pragma unroll
  for (int j = 0; j < 4; j++) v[j] = (base + j < N_NODES) ? deg[base + j] : 0;
  int tsum = v[0] + v[1] + v[2] + v[3];
  ls[t] = tsum;
  __syncthreads();
  for (int off = 1; off < 256; off <<= 1) {
    int add = (t >= off) ? ls[t - off] : 0;
    __syncthreads();
    ls[t] += add;
    __syncthreads();
  }
  int excl = ls[t] - tsum + part[blockIdx.x];
#pragma unroll
  for (int j = 0; j < 4; j++) {
    int idx = base + j;
    if (idx < N_NODES) { row_ptr[idx] = excl; cursor[idx] = excl; }
    excl += v[j];
  }
}

__global__ void __launch_bounds__(256) k_fill(const int* __restrict__ edge, int* __restrict__ cursor,
                                              int* __restrict__ col) {
  int i = blockIdx.x * 256 + threadIdx.x;
  int s, d;
  if (i < N_EDGES) { s = edge[i]; d = edge[N_EDGES + i]; }
  else if (i < ETOT) { s = i - N_EDGES; d = s; }
  else return;
  int pos = atomicAdd(&cursor[d], 1);
  col[pos] = s;
}

// ---------------- GEMM1: h1 = x @ W1  [N,128]x[128,256], fused att dots, bf16 out ----------------
__global__ void __launch_bounds__(256) k_gemm1(const float* __restrict__ x, const float* __restrict__ W1,
                                               const float* __restrict__ attS, const float* __restrict__ attD,
                                               unsigned short* __restrict__ h1b, float* __restrict__ aS,
                                               float* __restrict__ aD) {
  __shared__ float xs[64][128];
  int tid = threadIdx.x;
  int colg = tid & 63;       // 64 col groups of 4 cols
  int rowg = tid >> 6;       // 4 row groups of 16 rows
  int row0 = blockIdx.x * 64;
#pragma unroll
  for (int i = 0; i < 8; i++) {
    int idx = tid + i * 256;           // float4 index, 2048 total
    int r = idx >> 5;                  // 32 float4 per row
    int k4 = idx & 31;
    int gr = row0 + r; if (gr >= N_NODES) gr = N_NODES - 1;
    ((float4*)xs)[idx] = ((const float4*)(x + (size_t)gr * IN_CH))[k4];
  }
  __syncthreads();
  float acc[16][4] = {};
  int j0 = colg * 4;
  for (int k = 0; k < IN_CH; k += 4) {
    float4 w0 = *(const float4*)(W1 + (size_t)(k + 0) * C1 + j0);
    float4 w1 = *(const float4*)(W1 + (size_t)(k + 1) * C1 + j0);
    float4 w2 = *(const float4*)(W1 + (size_t)(k + 2) * C1 + j0);
    float4 w3 = *(const float4*)(W1 + (size_t)(k + 3) * C1 + j0);
#pragma unroll
    for (int r = 0; r < 16; r++) {
      float4 xv = *(const float4*)(&xs[rowg * 16 + r][k]);
      acc[r][0] += xv.x * w0.x + xv.y * w1.x + xv.z * w2.x + xv.w * w3.x;
      acc[r][1] += xv.x * w0.y + xv.y * w1.y + xv.z * w2.y + xv.w * w3.y;
      acc[r][2] += xv.x * w0.z + xv.y * w1.z + xv.z * w2.z + xv.w * w3.z;
      acc[r][3] += xv.x * w0.w + xv.y * w1.w + xv.z * w2.w + xv.w * w3.w;
    }
  }
  int head = colg >> 4;
  int cc = (colg & 15) * 4;
  float4 as4 = *(const float4*)(attS + head * HID + cc);
  float4 ad4 = *(const float4*)(attD + head * HID + cc);
#pragma unroll
  for (int r = 0; r < 16; r++) {
    int gr = row0 + rowg * 16 + r;
    if (gr < N_NODES) {
      ushort4 hv;
      hv.x = f2bf(acc[r][0]); hv.y = f2bf(acc[r][1]);
      hv.z = f2bf(acc[r][2]); hv.w = f2bf(acc[r][3]);
      *(ushort4*)(h1b + (size_t)gr * C1 + j0) = hv;
    }
    float s = acc[r][0] * as4.x + acc[r][1] * as4.y + acc[r][2] * as4.z + acc[r][3] * as4.w;
    float d = acc[r][0] * ad4.x + acc[r][1] * ad4.y + acc[r][2] * ad4.z + acc[r][3] * ad4.w;
#pragma unroll
    for (int m = 1; m <= 8; m <<= 1) { s += __shfl_xor(s, m, 64); d += __shfl_xor(d, m, 64); }
    if ((colg & 15) == 0 && gr < N_NODES) {
      aS[(size_t)gr * 4 + head] = s;
      aD[(size_t)gr * 4 + head] = d;
    }
  }
}

// ---------------- layer-1 aggregate (online softmax, bf16 gather) + bias + BN1 + ELU ----------------
__global__ void __launch_bounds__(256) k_agg1(const int* __restrict__ row_ptr, const int* __restrict__ col,
                                              const float* __restrict__ aS, const float* __restrict__ aD,
                                              const unsigned short* __restrict__ h1b, const float* __restrict__ b1,
                                              const float* __restrict__ g1, const float* __restrict__ be1,
                                              const float* __restrict__ m1, const float* __restrict__ v1,
                                              float* __restrict__ hm) {
  int wave = threadIdx.x >> 6;
  int lane = threadIdx.x & 63;
  int d = blockIdx.x * 4 + wave;
  if (d >= N_NODES) return;
  int head = lane >> 4;
  float ad = aD[(size_t)d * 4 + head];
  int s0 = row_ptr[d], s1 = row_ptr[d + 1];
  float mx = -INFINITY, denom = 0.f;
  float4 acc = {0.f, 0.f, 0.f, 0.f};
  int c0 = lane * 4;
  for (int i = s0; i < s1; i++) {
    int s = col[i];
    float e = leaky(aS[(size_t)s * 4 + head] + ad);
    float mn = fmaxf(mx, e);
    float corr = expf(mx - mn);   // 0 on first iter (exp(-inf)), 1 when max unchanged
    float w = expf(e - mn);
    ushort4 hv = *(const ushort4*)(h1b + (size_t)s * C1 + c0);
    denom = denom * corr + w;
    acc.x = acc.x * corr + w * bf2f(hv.x);
    acc.y = acc.y * corr + w * bf2f(hv.y);
    acc.z = acc.z * corr + w * bf2f(hv.z);
    acc.w = acc.w * corr + w * bf2f(hv.w);
    mx = mn;
  }
  float inv = 1.f / (denom + 1e-16f);
  float4 bb = *(const float4*)(b1 + c0);
  float4 gg = *(const float4*)(g1 + c0);
  float4 be = *(const float4*)(be1 + c0);
  float4 mm = *(const float4*)(m1 + c0);
  float4 vv = *(const float4*)(v1 + c0);
  float4 o;
  o.x = elu_f((acc.x * inv + bb.x - mm.x) * rsqrtf(vv.x + BN_EPS) * gg.x + be.x);
  o.y = elu_f((acc.y * inv + bb.y - mm.y) * rsqrtf(vv.y + BN_EPS) * gg.y + be.y);
  o.z = elu_f((acc.z * inv + bb.z - mm.z) * rsqrtf(vv.z + BN_EPS) * gg.z + be.z);
  o.w = elu_f((acc.w * inv + bb.w - mm.w) * rsqrtf(vv.w + BN_EPS) * gg.w + be.w);
  *(float4*)(hm + (size_t)d * C1 + c0) = o;
}

// ---------------- GEMM2: h2 = hm @ W2  [N,256]x[256,64], fused att dots ----------------
__global__ void __launch_bounds__(256) k_gemm2(const float* __restrict__ hm, const float* __restrict__ W2,
                                               const float* __restrict__ attS, const float* __restrict__ attD,
                                               float* __restrict__ h2, float* __restrict__ aS,
                                               float* __restrict__ aD) {
  __shared__ float xs[64][256];    // 64 KB
  int tid = threadIdx.x;
  int colg = tid & 31;     // 32 col groups of 2 cols
  int rowg = tid >> 5;     // 8 row groups of 8 rows
  int row0 = blockIdx.x * 64;
#pragma unroll
  for (int i = 0; i < 16; i++) {
    int idx = tid + i * 256;     // float4 index, 4096 total
    int r = idx >> 6;            // 64 float4 per row
    int k4 = idx & 63;
    int gr = row0 + r; if (gr >= N_NODES) gr = N_NODES - 1;
    ((float4*)xs)[idx] = ((const float4*)(hm + (size_t)gr * C1))[k4];
  }
  __syncthreads();
  float acc[8][2] = {};
  int c0 = colg * 2;
  for (int k = 0; k < C1; k += 4) {
    float2 w0 = *(const float2*)(W2 + (size_t)(k + 0) * HID + c0);
    float2 w1 = *(const float2*)(W2 + (size_t)(k + 1) * HID + c0);
    float2 w2 = *(const float2*)(W2 + (size_t)(k + 2) * HID + c0);
    float2 w3 = *(const float2*)(W2 + (size_t)(k + 3) * HID + c0);
#pragma unroll
    for (int r = 0; r < 8; r++) {
      float4 xv = *(const float4*)(&xs[rowg * 8 + r][k]);
      acc[r][0] += xv.x * w0.x + xv.y * w1.x + xv.z * w2.x + xv.w * w3.x;
      acc[r][1] += xv.x * w0.y + xv.y * w1.y + xv.z * w2.y + xv.w * w3.y;
    }
  }
  float2 as2 = *(const float2*)(attS + c0);
  float2 ad2 = *(const float2*)(attD + c0);
#pragma unroll
  for (int r = 0; r < 8; r++) {
    int gr = row0 + rowg * 8 + r;
    if (gr < N_NODES) *(float2*)(h2 + (size_t)gr * HID + c0) = make_float2(acc[r][0], acc[r][1]);
    float s = acc[r][0] * as2.x + acc[r][1] * as2.y;
    float d = acc[r][0] * ad2.x + acc[r][1] * ad2.y;
#pragma unroll
    for (int m = 1; m <= 16; m <<= 1) { s += __shfl_xor(s, m, 64); d += __shfl_xor(d, m, 64); }
    if (colg == 0 && gr < N_NODES) { aS[gr] = s; aD[gr] = d; }
  }
}

// ---------------- layer-2 aggregate (online softmax) + bias + BN2 + ELU -> node_emb ----------------
__global__ void __launch_bounds__(256) k_agg2(const int* __restrict__ row_ptr, const int* __restrict__ col,
                                              const float* __restrict__ aS, const float* __restrict__ aD,
                                              const float* __restrict__ h2, const float* __restrict__ b2,
                                              const float* __restrict__ g2, const float* __restrict__ be2,
                                              const float* __restrict__ m2, const float* __restrict__ v2,
                                              float* __restrict__ emb) {
  int wave = threadIdx.x >> 6;
  int lane = threadIdx.x & 63;
  int d = blockIdx.x * 4 + wave;
  if (d >= N_NODES) return;
  float ad = aD[d];
  int s0 = row_ptr[d], s1 = row_ptr[d + 1];
  float mx = -INFINITY, denom = 0.f, acc = 0.f;
  for (int i = s0; i < s1; i++) {
    int s = col[i];
    float e = leaky(aS[s] + ad);
    float mn = fmaxf(mx, e);
    float corr = expf(mx - mn);
    float w = expf(e - mn);
    float hv = h2[(size_t)s * HID + lane];
    denom = denom * corr + w;
    acc = acc * corr + w * hv;
    mx = mn;
  }
  float o = acc / (denom + 1e-16f) + b2[lane];
  o = (o - m2[lane]) * rsqrtf(v2[lane] + BN_EPS) * g2[lane] + be2[lane];
  emb[(size_t)d * HID + lane] = elu_f(o);
}

// ---------------- pooling partials ----------------
__global__ void __launch_bounds__(256) k_pool(const float* __restrict__ emb, float* __restrict__ psum,
                                              float* __restrict__ pmax) {
  __shared__ float ss[4][64], sm[4][64];
  int t = threadIdx.x;
  int c = t & 63, rg = t >> 6;
  float s = 0.f, m = -INFINITY;
  for (int n = blockIdx.x * 4 + rg; n < N_NODES; n += gridDim.x * 4) {
    float v = emb[(size_t)n * HID + c];
    s += v; m = fmaxf(m, v);
  }
  ss[rg][c] = s; sm[rg][c] = m;
  __syncthreads();
  if (t < 64) {
    psum[blockIdx.x * 64 + t] = ss[0][t] + ss[1][t] + ss[2][t] + ss[3][t];
    pmax[blockIdx.x * 64 + t] = fmaxf(fmaxf(sm[0][t], sm[1][t]), fmaxf(sm[2][t], sm[3][t]));
  }
}

// ---------------- final reduce + classifier ----------------
__global__ void __launch_bounds__(256) k_final(const float* __restrict__ psum, const float* __restrict__ pmax,
                                               const float* __restrict__ emb, const int* __restrict__ rootp,
                                               const float* __restrict__ cg1w, const float* __restrict__ cg1b,
                                               const float* __restrict__ cbng, const float* __restrict__ cbnb,
                                               const float* __restrict__ cbnm, const float* __restrict__ cbnv,
                                               const float* __restrict__ cg2w, const float* __restrict__ cg2b,
                                               const float* __restrict__ cg3w, const float* __restrict__ cg3b,
                                               float* __restrict__ out) {
  __shared__ float ss[4][64], sm[4][64];
  __shared__ float g[192], t1[64], t2[32];
  int t = threadIdx.x;
  int c = t & 63, q = t >> 6;
  float s = 0.f, m = -INFINITY;
  for (int b = q; b < 256; b += 4) {
    s += psum[b * 64 + c];
    m = fmaxf(m, pmax[b * 64 + c]);
  }
  ss[q][c] = s; sm[q][c] = m;
  __syncthreads();
  if (t < 64) {
    float tot = ss[0][t] + ss[1][t] + ss[2][t] + ss[3][t];
    float mx = fmaxf(fmaxf(sm[0][t], sm[1][t]), fmaxf(sm[2][t], sm[3][t]));
    int root = rootp[0];
    if (root > N_NODES - 1) root = N_NODES - 1;
    if (root < 0) root = 0;
    g[t] = tot / (float)N_NODES;
    g[64 + t] = mx;
    g[128 + t] = emb[(size_t)root * HID + t];
  }
  __syncthreads();
  if (t < 64) {
    float o = cg1b[t];
    for (int i = 0; i < 192; i++) o += g[i] * cg1w[i * 64 + t];
    o = (o - cbnm[t]) * rsqrtf(cbnv[t] + BN_EPS) * cbng[t] + cbnb[t];
    t1[t] = o > 0.f ? o : 0.f;
  }
  __syncthreads();
  if (t < 32) {
    float o = cg2b[t];
    for (int i = 0; i < 64; i++) o += t1[i] * cg2w[i * 32 + t];
    t2[t] = o > 0.f ? o : 0.f;
  }
  __syncthreads();
  if (t == 0) {
    float o = cg3b[0];
    for (int i = 0; i < 32; i++) o += t2[i] * cg3w[i];
    out[0] = o;
  }
}

extern "C" void kernel_launch(void* const* d_in, const int* in_sizes, int n_in,
                              void* d_out, int out_size, void* d_ws, size_t ws_size,
                              hipStream_t stream) {
  const float* x     = (const float*)d_in[0];
  const int*   edge  = (const int*)d_in[1];
  const int*   root  = (const int*)d_in[2];
  const float* W1    = (const float*)d_in[3];
  const float* attS1 = (const float*)d_in[4];
  const float* attD1 = (const float*)d_in[5];
  const float* b1    = (const float*)d_in[6];
  const float* W2    = (const float*)d_in[7];
  const float* attS2 = (const float*)d_in[8];
  const float* attD2 = (const float*)d_in[9];
  const float* b2    = (const float*)d_in[10];
  const float* bn1g  = (const float*)d_in[11];
  const float* bn1b  = (const float*)d_in[12];
  const float* bn1m  = (const float*)d_in[13];
  const float* bn1v  = (const float*)d_in[14];
  const float* bn2g  = (const float*)d_in[15];
  const float* bn2b  = (const float*)d_in[16];
  const float* bn2m  = (const float*)d_in[17];
  const float* bn2v  = (const float*)d_in[18];
  const float* cg1w  = (const float*)d_in[19];
  const float* cg1b  = (const float*)d_in[20];
  const float* cbng  = (const float*)d_in[21];
  const float* cbnb  = (const float*)d_in[22];
  const float* cbnm  = (const float*)d_in[23];
  const float* cbnv  = (const float*)d_in[24];
  const float* cg2w  = (const float*)d_in[25];
  const float* cg2b  = (const float*)d_in[26];
  const float* cg3w  = (const float*)d_in[27];
  const float* cg3b  = (const float*)d_in[28];

  // workspace arena (256B aligned blocks)
  char* ws = (char*)d_ws;
  size_t off = 0;
  auto carve = [&](size_t bytes) { char* p = ws + off; off += (bytes + 255) & ~(size_t)255; return p; };
  unsigned short* h1b = (unsigned short*)carve((size_t)N_NODES * C1 * 2);  // 51.2 MB
  float* hm      = (float*)carve((size_t)N_NODES * C1 * 4);                // 102.4 MB
  float* aS1     = (float*)carve((size_t)N_NODES * 4 * 4);
  float* aD1     = (float*)carve((size_t)N_NODES * 4 * 4);
  int*   deg     = (int*)  carve((size_t)N_NODES * 4);
  int*   row_ptr = (int*)  carve((size_t)(N_NODES + 1) * 4);
  int*   cursor  = (int*)  carve((size_t)N_NODES * 4);
  int*   col     = (int*)  carve((size_t)ETOT * 4);
  int*   part    = (int*)  carve(512);
  // layer-2 buffers alias regions that are dead by the time they're written:
  // h2/aS2/aD2 live in h1b's region (dead after k_agg1 reads it);
  // emb/psum/pmax live in hm's region (dead after k_gemm2 reads it).
  float* h2   = (float*)h1b;                         // N*64 f32 = 25.6 MB < 51.2
  float* aS2  = h2 + (size_t)N_NODES * HID;          // N
  float* aD2  = aS2 + N_NODES;
  float* emb  = hm;                                  // N*64 f32 = 25.6 MB < 102.4
  float* psum = emb + (size_t)N_NODES * HID;         // 256*64
  float* pmax = psum + 256 * 64;

  // CSR build
  k_init_deg<<<(N_NODES + 255) / 256, 256, 0, stream>>>(deg);
  k_deg<<<(N_EDGES + 255) / 256, 256, 0, stream>>>(edge, deg);
  k_scan_part<<<NCHUNK, 256, 0, stream>>>(deg, part);
  k_scan_top<<<1, 64, 0, stream>>>(part, row_ptr);
  k_scan_down<<<NCHUNK, 256, 0, stream>>>(deg, part, row_ptr, cursor);
  k_fill<<<(ETOT + 255) / 256, 256, 0, stream>>>(edge, cursor, col);
  // layer 1
  k_gemm1<<<(N_NODES + 63) / 64, 256, 0, stream>>>(x, W1, attS1, attD1, h1b, aS1, aD1);
  k_agg1<<<(N_NODES + 3) / 4, 256, 0, stream>>>(row_ptr, col, aS1, aD1, h1b, b1, bn1g, bn1b, bn1m, bn1v, hm);
  // layer 2
  k_gemm2<<<(N_NODES + 63) / 64, 256, 0, stream>>>(hm, W2, attS2, attD2, h2, aS2, aD2);
  k_agg2<<<(N_NODES + 3) / 4, 256, 0, stream>>>(row_ptr, col, aS2, aD2, h2, b2, bn2g, bn2b, bn2m, bn2v, emb);
  // pooling + classifier
  k_pool<<<256, 256, 0, stream>>>(emb, psum, pmax);
  k_final<<<1, 256, 0, stream>>>(psum, pmax, emb, root, cg1w, cg1b, cbng, cbnb, cbnm, cbnv,
                                 cg2w, cg2b, cg3w, cg3b, (float*)d_out);
}

// Round 3
// 786.571 us; speedup vs baseline: 1.3082x; 1.0483x over previous
//
#include <hip/hip_runtime.h>

#define N_NODES 100000
#define N_EDGES 1600000
#define ETOT    1700000   // edges + self loops
#define IN_CH   128
#define C1      256       // HEADS*HID
#define HID     64
#define BN_EPS  1e-5f
#define SLOPE   0.2f
#define NCHUNK  98        // ceil(N/1024)

__device__ __forceinline__ float leaky(float x) { return fmaxf(x, SLOPE * x); }
__device__ __forceinline__ float elu_f(float x) { return x > 0.f ? x : __expf(x) - 1.f; }
__device__ __forceinline__ unsigned short f2bf(float f) {   // RNE fp32->bf16
  unsigned int b = __float_as_uint(f);
  return (unsigned short)((b + 0x7FFFu + ((b >> 16) & 1u)) >> 16);
}
__device__ __forceinline__ float bf2f(unsigned short u) {
  return __uint_as_float((unsigned int)u << 16);
}

// ---------------- CSR build ----------------
__global__ void __launch_bounds__(256) k_init_deg(int* __restrict__ deg) {
  int n = blockIdx.x * 256 + threadIdx.x;
  if (n < N_NODES) deg[n] = 1;  // self loop
}

__global__ void __launch_bounds__(256) k_deg(const int* __restrict__ edge, int* __restrict__ deg) {
  int i = blockIdx.x * 256 + threadIdx.x;
  if (i < N_EDGES) atomicAdd(&deg[edge[N_EDGES + i]], 1);
}

__global__ void __launch_bounds__(256) k_scan_part(const int* __restrict__ deg, int* __restrict__ part) {
  __shared__ int ls[256];
  int t = threadIdx.x;
  int base = blockIdx.x * 1024 + t * 4;
  int s = 0;
#pragma unroll
  for (int j = 0; j < 4; j++) if (base + j < N_NODES) s += deg[base + j];
  ls[t] = s;
  __syncthreads();
  for (int off = 128; off >= 1; off >>= 1) {
    if (t < off) ls[t] += ls[t + off];
    __syncthreads();
  }
  if (t == 0) part[blockIdx.x] = ls[0];
}

__global__ void k_scan_top(int* __restrict__ part, int* __restrict__ row_ptr) {
  if (threadIdx.x == 0 && blockIdx.x == 0) {
    int run = 0;
    for (int i = 0; i < NCHUNK; i++) { int t = part[i]; part[i] = run; run += t; }
    row_ptr[N_NODES] = run;   // == ETOT
  }
}

__global__ void __launch_bounds__(256) k_scan_down(const int* __restrict__ deg, const int* __restrict__ part,
                                                   int* __restrict__ row_ptr, int* __restrict__ cursor) {
  __shared__ int ls[256];
  int t = threadIdx.x;
  int base = blockIdx.x * 1024 + t * 4;
  int v[4];
#pragma unroll
  for (int j = 0; j < 4; j++) v[j] = (base + j < N_NODES) ? deg[base + j] : 0;
  int tsum = v[0] + v[1] + v[2] + v[3];
  ls[t] = tsum;
  __syncthreads();
  for (int off = 1; off < 256; off <<= 1) {
    int add = (t >= off) ? ls[t - off] : 0;
    __syncthreads();
    ls[t] += add;
    __syncthreads();
  }
  int excl = ls[t] - tsum + part[blockIdx.x];
#pragma unroll
  for (int j = 0; j < 4; j++) {
    int idx = base + j;
    if (idx < N_NODES) { row_ptr[idx] = excl; cursor[idx] = excl; }
    excl += v[j];
  }
}

__global__ void __launch_bounds__(256) k_fill(const int* __restrict__ edge, int* __restrict__ cursor,
                                              int* __restrict__ col) {
  int i = blockIdx.x * 256 + threadIdx.x;
  int s, d;
  if (i < N_EDGES) { s = edge[i]; d = edge[N_EDGES + i]; }
  else if (i < ETOT) { s = i - N_EDGES; d = s; }
  else return;
  int pos = atomicAdd(&cursor[d], 1);
  col[pos] = s;
}

// ---------------- GEMM1: h1 = x @ W1  [N,128]x[128,256], fused att dots, bf16 out ----------------
__global__ void __launch_bounds__(256) k_gemm1(const float* __restrict__ x, const float* __restrict__ W1,
                                               const float* __restrict__ attS, const float* __restrict__ attD,
                                               unsigned short* __restrict__ h1b, float* __restrict__ aS,
                                               float* __restrict__ aD) {
  __shared__ float xs[64][128];
  int tid = threadIdx.x;
  int colg = tid & 63;       // 64 col groups of 4 cols
  int rowg = tid >> 6;       // 4 row groups of 16 rows
  int row0 = blockIdx.x * 64;
#pragma unroll
  for (int i = 0; i < 8; i++) {
    int idx = tid + i * 256;           // float4 index, 2048 total
    int r = idx >> 5;                  // 32 float4 per row
    int k4 = idx & 31;
    int gr = row0 + r; if (gr >= N_NODES) gr = N_NODES - 1;
    ((float4*)xs)[idx] = ((const float4*)(x + (size_t)gr * IN_CH))[k4];
  }
  __syncthreads();
  float acc[16][4] = {};
  int j0 = colg * 4;
  for (int k = 0; k < IN_CH; k += 4) {
    float4 w0 = *(const float4*)(W1 + (size_t)(k + 0) * C1 + j0);
    float4 w1 = *(const float4*)(W1 + (size_t)(k + 1) * C1 + j0);
    float4 w2 = *(const float4*)(W1 + (size_t)(k + 2) * C1 + j0);
    float4 w3 = *(const float4*)(W1 + (size_t)(k + 3) * C1 + j0);
#pragma unroll
    for (int r = 0; r < 16; r++) {
      float4 xv = *(const float4*)(&xs[rowg * 16 + r][k]);
      acc[r][0] += xv.x * w0.x + xv.y * w1.x + xv.z * w2.x + xv.w * w3.x;
      acc[r][1] += xv.x * w0.y + xv.y * w1.y + xv.z * w2.y + xv.w * w3.y;
      acc[r][2] += xv.x * w0.z + xv.y * w1.z + xv.z * w2.z + xv.w * w3.z;
      acc[r][3] += xv.x * w0.w + xv.y * w1.w + xv.z * w2.w + xv.w * w3.w;
    }
  }
  int head = colg >> 4;
  int cc = (colg & 15) * 4;
  float4 as4 = *(const float4*)(attS + head * HID + cc);
  float4 ad4 = *(const float4*)(attD + head * HID + cc);
#pragma unroll
  for (int r = 0; r < 16; r++) {
    int gr = row0 + rowg * 16 + r;
    if (gr < N_NODES) {
      ushort4 hv;
      hv.x = f2bf(acc[r][0]); hv.y = f2bf(acc[r][1]);
      hv.z = f2bf(acc[r][2]); hv.w = f2bf(acc[r][3]);
      *(ushort4*)(h1b + (size_t)gr * C1 + j0) = hv;
    }
    float s = acc[r][0] * as4.x + acc[r][1] * as4.y + acc[r][2] * as4.z + acc[r][3] * as4.w;
    float d = acc[r][0] * ad4.x + acc[r][1] * ad4.y + acc[r][2] * ad4.z + acc[r][3] * ad4.w;
#pragma unroll
    for (int m = 1; m <= 8; m <<= 1) { s += __shfl_xor(s, m, 64); d += __shfl_xor(d, m, 64); }
    if ((colg & 15) == 0 && gr < N_NODES) {
      aS[(size_t)gr * 4 + head] = s;
      aD[(size_t)gr * 4 + head] = d;
    }
  }
}

// ---------------- layer-1 aggregate (shift-free softmax, bf16 gather) + bias + BN1 + ELU ----------------
__global__ void __launch_bounds__(256) k_agg1(const int* __restrict__ row_ptr, const int* __restrict__ col,
                                              const float* __restrict__ aS, const float* __restrict__ aD,
                                              const unsigned short* __restrict__ h1b, const float* __restrict__ b1,
                                              const float* __restrict__ g1, const float* __restrict__ be1,
                                              const float* __restrict__ m1, const float* __restrict__ v1,
                                              float* __restrict__ hm) {
  int wave = threadIdx.x >> 6;
  int lane = threadIdx.x & 63;
  int d = blockIdx.x * 4 + wave;
  if (d >= N_NODES) return;
  int head = lane >> 4;
  float ad = aD[d * 4 + head];
  int s0 = row_ptr[d], s1 = row_ptr[d + 1];
  float denom = 0.f;
  float4 acc = {0.f, 0.f, 0.f, 0.f};
  int c0 = lane * 4;
  for (int i = s0; i < s1; i++) {
    int s = col[i];                               // wave-uniform
    const float* ap = aS + (s << 2);              // uniform base
    const unsigned short* rowp = h1b + (s << 8);  // uniform base
    float e = leaky(ap[head] + ad);
    float w = __expf(fminf(e, 80.f));             // shift-free: e std ~1.5, no overflow risk
    ushort4 hv = *(const ushort4*)(rowp + c0);
    denom += w;
    acc.x += w * bf2f(hv.x);
    acc.y += w * bf2f(hv.y);
    acc.z += w * bf2f(hv.z);
    acc.w += w * bf2f(hv.w);
  }
  float inv = 1.f / (denom + 1e-16f);
  float4 bb = *(const float4*)(b1 + c0);
  float4 gg = *(const float4*)(g1 + c0);
  float4 be = *(const float4*)(be1 + c0);
  float4 mm = *(const float4*)(m1 + c0);
  float4 vv = *(const float4*)(v1 + c0);
  float4 o;
  o.x = elu_f((acc.x * inv + bb.x - mm.x) * rsqrtf(vv.x + BN_EPS) * gg.x + be.x);
  o.y = elu_f((acc.y * inv + bb.y - mm.y) * rsqrtf(vv.y + BN_EPS) * gg.y + be.y);
  o.z = elu_f((acc.z * inv + bb.z - mm.z) * rsqrtf(vv.z + BN_EPS) * gg.z + be.z);
  o.w = elu_f((acc.w * inv + bb.w - mm.w) * rsqrtf(vv.w + BN_EPS) * gg.w + be.w);
  *(float4*)(hm + (size_t)d * C1 + c0) = o;
}

// ---------------- GEMM2: h2 = hm @ W2  [N,256]x[256,64], fused att dots, bf16 out ----------------
__global__ void __launch_bounds__(256) k_gemm2(const float* __restrict__ hm, const float* __restrict__ W2,
                                               const float* __restrict__ attS, const float* __restrict__ attD,
                                               unsigned short* __restrict__ h2b, float* __restrict__ aS,
                                               float* __restrict__ aD) {
  __shared__ float xs[64][256];    // 64 KB
  int tid = threadIdx.x;
  int colg = tid & 31;     // 32 col groups of 2 cols
  int rowg = tid >> 5;     // 8 row groups of 8 rows
  int row0 = blockIdx.x * 64;
#pragma unroll
  for (int i = 0; i < 16; i++) {
    int idx = tid + i * 256;     // float4 index, 4096 total
    int r = idx >> 6;            // 64 float4 per row
    int k4 = idx & 63;
    int gr = row0 + r; if (gr >= N_NODES) gr = N_NODES - 1;
    ((float4*)xs)[idx] = ((const float4*)(hm + (size_t)gr * C1))[k4];
  }
  __syncthreads();
  float acc[8][2] = {};
  int c0 = colg * 2;
  for (int k = 0; k < C1; k += 4) {
    float2 w0 = *(const float2*)(W2 + (size_t)(k + 0) * HID + c0);
    float2 w1 = *(const float2*)(W2 + (size_t)(k + 1) * HID + c0);
    float2 w2 = *(const float2*)(W2 + (size_t)(k + 2) * HID + c0);
    float2 w3 = *(const float2*)(W2 + (size_t)(k + 3) * HID + c0);
#pragma unroll
    for (int r = 0; r < 8; r++) {
      float4 xv = *(const float4*)(&xs[rowg * 8 + r][k]);
      acc[r][0] += xv.x * w0.x + xv.y * w1.x + xv.z * w2.x + xv.w * w3.x;
      acc[r][1] += xv.x * w0.y + xv.y * w1.y + xv.z * w2.y + xv.w * w3.y;
    }
  }
  float2 as2 = *(const float2*)(attS + c0);
  float2 ad2 = *(const float2*)(attD + c0);
#pragma unroll
  for (int r = 0; r < 8; r++) {
    int gr = row0 + rowg * 8 + r;
    if (gr < N_NODES) {
      ushort2 hv;
      hv.x = f2bf(acc[r][0]); hv.y = f2bf(acc[r][1]);
      *(ushort2*)(h2b + (size_t)gr * HID + c0) = hv;
    }
    float s = acc[r][0] * as2.x + acc[r][1] * as2.y;
    float d = acc[r][0] * ad2.x + acc[r][1] * ad2.y;
#pragma unroll
    for (int m = 1; m <= 16; m <<= 1) { s += __shfl_xor(s, m, 64); d += __shfl_xor(d, m, 64); }
    if (colg == 0 && gr < N_NODES) { aS[gr] = s; aD[gr] = d; }
  }
}

// ---------------- layer-2 aggregate (shift-free softmax, bf16 gather) + bias + BN2 + ELU ----------------
__global__ void __launch_bounds__(256) k_agg2(const int* __restrict__ row_ptr, const int* __restrict__ col,
                                              const float* __restrict__ aS, const float* __restrict__ aD,
                                              const unsigned short* __restrict__ h2b, const float* __restrict__ b2,
                                              const float* __restrict__ g2, const float* __restrict__ be2,
                                              const float* __restrict__ m2, const float* __restrict__ v2,
                                              float* __restrict__ emb) {
  int wave = threadIdx.x >> 6;
  int lane = threadIdx.x & 63;
  int d = blockIdx.x * 4 + wave;
  if (d >= N_NODES) return;
  float ad = aD[d];
  int s0 = row_ptr[d], s1 = row_ptr[d + 1];
  float denom = 0.f, acc = 0.f;
  for (int i = s0; i < s1; i++) {
    int s = col[i];                               // wave-uniform
    float e = leaky(aS[s] + ad);                  // uniform scalar load
    float w = __expf(fminf(e, 80.f));
    const unsigned short* rowp = h2b + (s << 6);  // uniform base
    float hv = bf2f(rowp[lane]);
    denom += w;
    acc += w * hv;
  }
  float o = acc / (denom + 1e-16f) + b2[lane];
  o = (o - m2[lane]) * rsqrtf(v2[lane] + BN_EPS) * g2[lane] + be2[lane];
  emb[(size_t)d * HID + lane] = elu_f(o);
}

// ---------------- pooling partials ----------------
__global__ void __launch_bounds__(256) k_pool(const float* __restrict__ emb, float* __restrict__ psum,
                                              float* __restrict__ pmax) {
  __shared__ float ss[4][64], sm[4][64];
  int t = threadIdx.x;
  int c = t & 63, rg = t >> 6;
  float s = 0.f, m = -INFINITY;
  for (int n = blockIdx.x * 4 + rg; n < N_NODES; n += gridDim.x * 4) {
    float v = emb[(size_t)n * HID + c];
    s += v; m = fmaxf(m, v);
  }
  ss[rg][c] = s; sm[rg][c] = m;
  __syncthreads();
  if (t < 64) {
    psum[blockIdx.x * 64 + t] = ss[0][t] + ss[1][t] + ss[2][t] + ss[3][t];
    pmax[blockIdx.x * 64 + t] = fmaxf(fmaxf(sm[0][t], sm[1][t]), fmaxf(sm[2][t], sm[3][t]));
  }
}

// ---------------- final reduce + classifier ----------------
__global__ void __launch_bounds__(256) k_final(const float* __restrict__ psum, const float* __restrict__ pmax,
                                               const float* __restrict__ emb, const int* __restrict__ rootp,
                                               const float* __restrict__ cg1w, const float* __restrict__ cg1b,
                                               const float* __restrict__ cbng, const float* __restrict__ cbnb,
                                               const float* __restrict__ cbnm, const float* __restrict__ cbnv,
                                               const float* __restrict__ cg2w, const float* __restrict__ cg2b,
                                               const float* __restrict__ cg3w, const float* __restrict__ cg3b,
                                               float* __restrict__ out) {
  __shared__ float ss[4][64], sm[4][64];
  __shared__ float g[192], t1[64], t2[32];
  int t = threadIdx.x;
  int c = t & 63, q = t >> 6;
  float s = 0.f, m = -INFINITY;
  for (int b = q; b < 256; b += 4) {
    s += psum[b * 64 + c];
    m = fmaxf(m, pmax[b * 64 + c]);
  }
  ss[q][c] = s; sm[q][c] = m;
  __syncthreads();
  if (t < 64) {
    float tot = ss[0][t] + ss[1][t] + ss[2][t] + ss[3][t];
    float mx = fmaxf(fmaxf(sm[0][t], sm[1][t]), fmaxf(sm[2][t], sm[3][t]));
    int root = rootp[0];
    if (root > N_NODES - 1) root = N_NODES - 1;
    if (root < 0) root = 0;
    g[t] = tot / (float)N_NODES;
    g[64 + t] = mx;
    g[128 + t] = emb[(size_t)root * HID + t];
  }
  __syncthreads();
  if (t < 64) {
    float o = cg1b[t];
    for (int i = 0; i < 192; i++) o += g[i] * cg1w[i * 64 + t];
    o = (o - cbnm[t]) * rsqrtf(cbnv[t] + BN_EPS) * cbng[t] + cbnb[t];
    t1[t] = o > 0.f ? o : 0.f;
  }
  __syncthreads();
  if (t < 32) {
    float o = cg2b[t];
    for (int i = 0; i < 64; i++) o += t1[i] * cg2w[i * 32 + t];
    t2[t] = o > 0.f ? o : 0.f;
  }
  __syncthreads();
  if (t == 0) {
    float o = cg3b[0];
    for (int i = 0; i < 32; i++) o += t2[i] * cg3w[i];
    out[0] = o;
  }
}

extern "C" void kernel_launch(void* const* d_in, const int* in_sizes, int n_in,
                              void* d_out, int out_size, void* d_ws, size_t ws_size,
                              hipStream_t stream) {
  const float* x     = (const float*)d_in[0];
  const int*   edge  = (const int*)d_in[1];
  const int*   root  = (const int*)d_in[2];
  const float* W1    = (const float*)d_in[3];
  const float* attS1 = (const float*)d_in[4];
  const float* attD1 = (const float*)d_in[5];
  const float* b1    = (const float*)d_in[6];
  const float* W2    = (const float*)d_in[7];
  const float* attS2 = (const float*)d_in[8];
  const float* attD2 = (const float*)d_in[9];
  const float* b2    = (const float*)d_in[10];
  const float* bn1g  = (const float*)d_in[11];
  const float* bn1b  = (const float*)d_in[12];
  const float* bn1m  = (const float*)d_in[13];
  const float* bn1v  = (const float*)d_in[14];
  const float* bn2g  = (const float*)d_in[15];
  const float* bn2b  = (const float*)d_in[16];
  const float* bn2m  = (const float*)d_in[17];
  const float* bn2v  = (const float*)d_in[18];
  const float* cg1w  = (const float*)d_in[19];
  const float* cg1b  = (const float*)d_in[20];
  const float* cbng  = (const float*)d_in[21];
  const float* cbnb  = (const float*)d_in[22];
  const float* cbnm  = (const float*)d_in[23];
  const float* cbnv  = (const float*)d_in[24];
  const float* cg2w  = (const float*)d_in[25];
  const float* cg2b  = (const float*)d_in[26];
  const float* cg3w  = (const float*)d_in[27];
  const float* cg3b  = (const float*)d_in[28];

  // workspace arena (256B aligned blocks)
  char* ws = (char*)d_ws;
  size_t off = 0;
  auto carve = [&](size_t bytes) { char* p = ws + off; off += (bytes + 255) & ~(size_t)255; return p; };
  unsigned short* h1b = (unsigned short*)carve((size_t)N_NODES * C1 * 2);  // 51.2 MB
  float* hm      = (float*)carve((size_t)N_NODES * C1 * 4);                // 102.4 MB
  float* aS1     = (float*)carve((size_t)N_NODES * 4 * 4);
  float* aD1     = (float*)carve((size_t)N_NODES * 4 * 4);
  int*   deg     = (int*)  carve((size_t)N_NODES * 4);
  int*   row_ptr = (int*)  carve((size_t)(N_NODES + 1) * 4);
  int*   cursor  = (int*)  carve((size_t)N_NODES * 4);
  int*   col     = (int*)  carve((size_t)ETOT * 4);
  int*   part    = (int*)  carve(512);
  // layer-2 buffers alias regions that are dead by the time they're written:
  // h2b/aS2/aD2 live in h1b's region (dead after k_agg1 reads it);
  // emb/psum/pmax live in hm's region (dead after k_gemm2 reads it).
  unsigned short* h2b = h1b;                          // N*64 bf16 = 12.8 MB < 51.2
  float* aS2  = (float*)(h1b + (size_t)N_NODES * HID); // N
  float* aD2  = aS2 + N_NODES;
  float* emb  = hm;                                   // N*64 f32 = 25.6 MB < 102.4
  float* psum = emb + (size_t)N_NODES * HID;          // 256*64
  float* pmax = psum + 256 * 64;

  // CSR build
  k_init_deg<<<(N_NODES + 255) / 256, 256, 0, stream>>>(deg);
  k_deg<<<(N_EDGES + 255) / 256, 256, 0, stream>>>(edge, deg);
  k_scan_part<<<NCHUNK, 256, 0, stream>>>(deg, part);
  k_scan_top<<<1, 64, 0, stream>>>(part, row_ptr);
  k_scan_down<<<NCHUNK, 256, 0, stream>>>(deg, part, row_ptr, cursor);
  k_fill<<<(ETOT + 255) / 256, 256, 0, stream>>>(edge, cursor, col);
  // layer 1
  k_gemm1<<<(N_NODES + 63) / 64, 256, 0, stream>>>(x, W1, attS1, attD1, h1b, aS1, aD1);
  k_agg1<<<(N_NODES + 3) / 4, 256, 0, stream>>>(row_ptr, col, aS1, aD1, h1b, b1, bn1g, bn1b, bn1m, bn1v, hm);
  // layer 2
  k_gemm2<<<(N_NODES + 63) / 64, 256, 0, stream>>>(hm, W2, attS2, attD2, h2b, aS2, aD2);
  k_agg2<<<(N_NODES + 3) / 4, 256, 0, stream>>>(row_ptr, col, aS2, aD2, h2b, b2, bn2g, bn2b, bn2m, bn2v, emb);
  // pooling + classifier
  k_pool<<<256, 256, 0, stream>>>(emb, psum, pmax);
  k_final<<<1, 256, 0, stream>>>(psum, pmax, emb, root, cg1w, cg1b, cbng, cbnb, cbnm, cbnv,
                                 cg2w, cg2b, cg3w, cg3b, (float*)d_out);
}

// Round 4
// 641.863 us; speedup vs baseline: 1.6031x; 1.2254x over previous
//
#include <hip/hip_runtime.h>

#define N_NODES 100000
#define N_EDGES 1600000
#define ETOT    1700000   // edges + self loops
#define IN_CH   128
#define C1      256       // HEADS*HID
#define HID     64
#define BN_EPS  1e-5f
#define SLOPE   0.2f
#define NCHUNK  98        // ceil(N/1024)

__device__ __forceinline__ float leaky(float x) { return fmaxf(x, SLOPE * x); }
__device__ __forceinline__ float elu_f(float x) { return x > 0.f ? x : __expf(x) - 1.f; }
__device__ __forceinline__ unsigned short f2bf(float f) {   // RNE fp32->bf16
  unsigned int b = __float_as_uint(f);
  return (unsigned short)((b + 0x7FFFu + ((b >> 16) & 1u)) >> 16);
}
__device__ __forceinline__ float bf2f(unsigned short u) {
  return __uint_as_float((unsigned int)u << 16);
}

// ---------------- CSR build ----------------
__global__ void __launch_bounds__(256) k_init_deg(int* __restrict__ deg) {
  int n = blockIdx.x * 256 + threadIdx.x;
  if (n < N_NODES) deg[n] = 1;  // self loop
}

__global__ void __launch_bounds__(256) k_deg(const int* __restrict__ edge, int* __restrict__ deg) {
  int i = blockIdx.x * 256 + threadIdx.x;
  if (i < N_EDGES) atomicAdd(&deg[edge[N_EDGES + i]], 1);
}

__global__ void __launch_bounds__(256) k_scan_part(const int* __restrict__ deg, int* __restrict__ part) {
  __shared__ int ls[256];
  int t = threadIdx.x;
  int base = blockIdx.x * 1024 + t * 4;
  int s = 0;
#pragma unroll
  for (int j = 0; j < 4; j++) if (base + j < N_NODES) s += deg[base + j];
  ls[t] = s;
  __syncthreads();
  for (int off = 128; off >= 1; off >>= 1) {
    if (t < off) ls[t] += ls[t + off];
    __syncthreads();
  }
  if (t == 0) part[blockIdx.x] = ls[0];
}

__global__ void k_scan_top(int* __restrict__ part, int* __restrict__ row_ptr) {
  if (threadIdx.x == 0 && blockIdx.x == 0) {
    int run = 0;
    for (int i = 0; i < NCHUNK; i++) { int t = part[i]; part[i] = run; run += t; }
    row_ptr[N_NODES] = run;   // == ETOT
  }
}

__global__ void __launch_bounds__(256) k_scan_down(const int* __restrict__ deg, const int* __restrict__ part,
                                                   int* __restrict__ row_ptr, int* __restrict__ cursor) {
  __shared__ int ls[256];
  int t = threadIdx.x;
  int base = blockIdx.x * 1024 + t * 4;
  int v[4];
#pragma unroll
  for (int j = 0; j < 4; j++) v[j] = (base + j < N_NODES) ? deg[base + j] : 0;
  int tsum = v[0] + v[1] + v[2] + v[3];
  ls[t] = tsum;
  __syncthreads();
  for (int off = 1; off < 256; off <<= 1) {
    int add = (t >= off) ? ls[t - off] : 0;
    __syncthreads();
    ls[t] += add;
    __syncthreads();
  }
  int excl = ls[t] - tsum + part[blockIdx.x];
#pragma unroll
  for (int j = 0; j < 4; j++) {
    int idx = base + j;
    if (idx < N_NODES) { row_ptr[idx] = excl; cursor[idx] = excl; }
    excl += v[j];
  }
}

__global__ void __launch_bounds__(256) k_fill(const int* __restrict__ edge, int* __restrict__ cursor,
                                              int* __restrict__ col) {
  int i = blockIdx.x * 256 + threadIdx.x;
  int s, d;
  if (i < N_EDGES) { s = edge[i]; d = edge[N_EDGES + i]; }
  else if (i < ETOT) { s = i - N_EDGES; d = s; }
  else return;
  int pos = atomicAdd(&cursor[d], 1);
  col[pos] = s;
}

// ---------------- GEMM1: h1 = x @ W1  [N,128]x[128,256], fused att dots, bf16 out ----------------
__global__ void __launch_bounds__(256) k_gemm1(const float* __restrict__ x, const float* __restrict__ W1,
                                               const float* __restrict__ attS, const float* __restrict__ attD,
                                               unsigned short* __restrict__ h1b, float* __restrict__ aS,
                                               float* __restrict__ aD) {
  __shared__ float xs[64][128];
  int tid = threadIdx.x;
  int colg = tid & 63;       // 64 col groups of 4 cols
  int rowg = tid >> 6;       // 4 row groups of 16 rows
  int row0 = blockIdx.x * 64;
#pragma unroll
  for (int i = 0; i < 8; i++) {
    int idx = tid + i * 256;           // float4 index, 2048 total
    int r = idx >> 5;                  // 32 float4 per row
    int k4 = idx & 31;
    int gr = row0 + r; if (gr >= N_NODES) gr = N_NODES - 1;
    ((float4*)xs)[idx] = ((const float4*)(x + (size_t)gr * IN_CH))[k4];
  }
  __syncthreads();
  float acc[16][4] = {};
  int j0 = colg * 4;
  for (int k = 0; k < IN_CH; k += 4) {
    float4 w0 = *(const float4*)(W1 + (size_t)(k + 0) * C1 + j0);
    float4 w1 = *(const float4*)(W1 + (size_t)(k + 1) * C1 + j0);
    float4 w2 = *(const float4*)(W1 + (size_t)(k + 2) * C1 + j0);
    float4 w3 = *(const float4*)(W1 + (size_t)(k + 3) * C1 + j0);
#pragma unroll
    for (int r = 0; r < 16; r++) {
      float4 xv = *(const float4*)(&xs[rowg * 16 + r][k]);
      acc[r][0] += xv.x * w0.x + xv.y * w1.x + xv.z * w2.x + xv.w * w3.x;
      acc[r][1] += xv.x * w0.y + xv.y * w1.y + xv.z * w2.y + xv.w * w3.y;
      acc[r][2] += xv.x * w0.z + xv.y * w1.z + xv.z * w2.z + xv.w * w3.z;
      acc[r][3] += xv.x * w0.w + xv.y * w1.w + xv.z * w2.w + xv.w * w3.w;
    }
  }
  int head = colg >> 4;
  int cc = (colg & 15) * 4;
  float4 as4 = *(const float4*)(attS + head * HID + cc);
  float4 ad4 = *(const float4*)(attD + head * HID + cc);
#pragma unroll
  for (int r = 0; r < 16; r++) {
    int gr = row0 + rowg * 16 + r;
    if (gr < N_NODES) {
      ushort4 hv;
      hv.x = f2bf(acc[r][0]); hv.y = f2bf(acc[r][1]);
      hv.z = f2bf(acc[r][2]); hv.w = f2bf(acc[r][3]);
      *(ushort4*)(h1b + (size_t)gr * C1 + j0) = hv;
    }
    float s = acc[r][0] * as4.x + acc[r][1] * as4.y + acc[r][2] * as4.z + acc[r][3] * as4.w;
    float d = acc[r][0] * ad4.x + acc[r][1] * ad4.y + acc[r][2] * ad4.z + acc[r][3] * ad4.w;
#pragma unroll
    for (int m = 1; m <= 8; m <<= 1) { s += __shfl_xor(s, m, 64); d += __shfl_xor(d, m, 64); }
    if ((colg & 15) == 0 && gr < N_NODES) {
      aS[(size_t)gr * 4 + head] = s;
      aD[(size_t)gr * 4 + head] = d;
    }
  }
}

// ---------------- layer-1 aggregate: 4-deep pipelined gather, scalar bases, bf16 in/out ----------------
__global__ void __launch_bounds__(256) k_agg1(const int* __restrict__ row_ptr, const int* __restrict__ col,
                                              const float* __restrict__ aS, const float* __restrict__ aD,
                                              const unsigned short* __restrict__ h1b, const float* __restrict__ b1,
                                              const float* __restrict__ g1, const float* __restrict__ be1,
                                              const float* __restrict__ m1, const float* __restrict__ v1,
                                              unsigned short* __restrict__ hmb) {
  int wave = threadIdx.x >> 6;
  int lane = threadIdx.x & 63;
  int d = blockIdx.x * 4 + wave;
  if (d >= N_NODES) return;
  int head = lane >> 4;
  float ad = aD[d * 4 + head];
  int s0 = row_ptr[d], s1 = row_ptr[d + 1];
  float denom = 0.f;
  float4 acc = {0.f, 0.f, 0.f, 0.f};
  int c0 = lane * 4;
  int i = s0;
  int iend4 = s0 + ((s1 - s0) & ~3);
  for (; i < iend4; i += 4) {
    int cv = col[i + (lane & 3)];                  // one 16B segment, lanes 0-3 hold the 4 ids
    int sa = __builtin_amdgcn_readfirstlane(__shfl(cv, 0));
    int sb = __builtin_amdgcn_readfirstlane(__shfl(cv, 1));
    int sc = __builtin_amdgcn_readfirstlane(__shfl(cv, 2));
    int sd = __builtin_amdgcn_readfirstlane(__shfl(cv, 3));
    // issue all 8 loads before any use (MLP)
    float ea = aS[(sa << 2) + head];
    float eb = aS[(sb << 2) + head];
    float ec = aS[(sc << 2) + head];
    float ed = aS[(sd << 2) + head];
    ushort4 ha = *(const ushort4*)(h1b + ((size_t)sa << 8) + c0);
    ushort4 hb = *(const ushort4*)(h1b + ((size_t)sb << 8) + c0);
    ushort4 hc = *(const ushort4*)(h1b + ((size_t)sc << 8) + c0);
    ushort4 hd = *(const ushort4*)(h1b + ((size_t)sd << 8) + c0);
    float wa = __expf(fminf(leaky(ea + ad), 80.f));
    float wb = __expf(fminf(leaky(eb + ad), 80.f));
    float wc = __expf(fminf(leaky(ec + ad), 80.f));
    float wd = __expf(fminf(leaky(ed + ad), 80.f));
    denom += (wa + wb) + (wc + wd);
    acc.x += wa * bf2f(ha.x) + wb * bf2f(hb.x) + wc * bf2f(hc.x) + wd * bf2f(hd.x);
    acc.y += wa * bf2f(ha.y) + wb * bf2f(hb.y) + wc * bf2f(hc.y) + wd * bf2f(hd.y);
    acc.z += wa * bf2f(ha.z) + wb * bf2f(hb.z) + wc * bf2f(hc.z) + wd * bf2f(hd.z);
    acc.w += wa * bf2f(ha.w) + wb * bf2f(hb.w) + wc * bf2f(hc.w) + wd * bf2f(hd.w);
  }
  for (; i < s1; i++) {
    int s = __builtin_amdgcn_readfirstlane(col[i]);
    float e = aS[(s << 2) + head];
    ushort4 hv = *(const ushort4*)(h1b + ((size_t)s << 8) + c0);
    float w = __expf(fminf(leaky(e + ad), 80.f));
    denom += w;
    acc.x += w * bf2f(hv.x);
    acc.y += w * bf2f(hv.y);
    acc.z += w * bf2f(hv.z);
    acc.w += w * bf2f(hv.w);
  }
  float inv = 1.f / (denom + 1e-16f);
  float4 bb = *(const float4*)(b1 + c0);
  float4 gg = *(const float4*)(g1 + c0);
  float4 be = *(const float4*)(be1 + c0);
  float4 mm = *(const float4*)(m1 + c0);
  float4 vv = *(const float4*)(v1 + c0);
  ushort4 o;
  o.x = f2bf(elu_f((acc.x * inv + bb.x - mm.x) * rsqrtf(vv.x + BN_EPS) * gg.x + be.x));
  o.y = f2bf(elu_f((acc.y * inv + bb.y - mm.y) * rsqrtf(vv.y + BN_EPS) * gg.y + be.y));
  o.z = f2bf(elu_f((acc.z * inv + bb.z - mm.z) * rsqrtf(vv.z + BN_EPS) * gg.z + be.z));
  o.w = f2bf(elu_f((acc.w * inv + bb.w - mm.w) * rsqrtf(vv.w + BN_EPS) * gg.w + be.w));
  *(ushort4*)(hmb + (size_t)d * C1 + c0) = o;
}

// ---------------- GEMM2: h2 = hm @ W2  [N,256]x[256,64], bf16 in, fused att dots, bf16 out ----------------
__global__ void __launch_bounds__(256) k_gemm2(const unsigned short* __restrict__ hmb, const float* __restrict__ W2,
                                               const float* __restrict__ attS, const float* __restrict__ attD,
                                               unsigned short* __restrict__ h2b, float* __restrict__ aS,
                                               float* __restrict__ aD) {
  __shared__ float xs[64][256];    // 64 KB fp32 staging
  int tid = threadIdx.x;
  int colg = tid & 31;     // 32 col groups of 2 cols
  int rowg = tid >> 5;     // 8 row groups of 8 rows
  int row0 = blockIdx.x * 64;
#pragma unroll
  for (int i = 0; i < 8; i++) {
    int idx = tid + i * 256;     // 16B (8 bf16) chunk id, 2048 total
    int r = idx >> 5;            // 32 chunks per row
    int k8 = (idx & 31) * 8;
    int gr = row0 + r; if (gr >= N_NODES) gr = N_NODES - 1;
    uint4 u = *(const uint4*)(hmb + (size_t)gr * C1 + k8);
    float4 lo, hi;
    lo.x = __uint_as_float(u.x << 16);  lo.y = __uint_as_float(u.x & 0xFFFF0000u);
    lo.z = __uint_as_float(u.y << 16);  lo.w = __uint_as_float(u.y & 0xFFFF0000u);
    hi.x = __uint_as_float(u.z << 16);  hi.y = __uint_as_float(u.z & 0xFFFF0000u);
    hi.z = __uint_as_float(u.w << 16);  hi.w = __uint_as_float(u.w & 0xFFFF0000u);
    *(float4*)&xs[r][k8]     = lo;
    *(float4*)&xs[r][k8 + 4] = hi;
  }
  __syncthreads();
  float acc[8][2] = {};
  int c0 = colg * 2;
  for (int k = 0; k < C1; k += 4) {
    float2 w0 = *(const float2*)(W2 + (size_t)(k + 0) * HID + c0);
    float2 w1 = *(const float2*)(W2 + (size_t)(k + 1) * HID + c0);
    float2 w2 = *(const float2*)(W2 + (size_t)(k + 2) * HID + c0);
    float2 w3 = *(const float2*)(W2 + (size_t)(k + 3) * HID + c0);
#pragma unroll
    for (int r = 0; r < 8; r++) {
      float4 xv = *(const float4*)(&xs[rowg * 8 + r][k]);
      acc[r][0] += xv.x * w0.x + xv.y * w1.x + xv.z * w2.x + xv.w * w3.x;
      acc[r][1] += xv.x * w0.y + xv.y * w1.y + xv.z * w2.y + xv.w * w3.y;
    }
  }
  float2 as2 = *(const float2*)(attS + c0);
  float2 ad2 = *(const float2*)(attD + c0);
#pragma unroll
  for (int r = 0; r < 8; r++) {
    int gr = row0 + rowg * 8 + r;
    if (gr < N_NODES) {
      ushort2 hv;
      hv.x = f2bf(acc[r][0]); hv.y = f2bf(acc[r][1]);
      *(ushort2*)(h2b + (size_t)gr * HID + c0) = hv;
    }
    float s = acc[r][0] * as2.x + acc[r][1] * as2.y;
    float d = acc[r][0] * ad2.x + acc[r][1] * ad2.y;
#pragma unroll
    for (int m = 1; m <= 16; m <<= 1) { s += __shfl_xor(s, m, 64); d += __shfl_xor(d, m, 64); }
    if (colg == 0 && gr < N_NODES) { aS[gr] = s; aD[gr] = d; }
  }
}

// ---------------- layer-2 aggregate: 4-deep pipelined gather, scalar bases ----------------
__global__ void __launch_bounds__(256) k_agg2(const int* __restrict__ row_ptr, const int* __restrict__ col,
                                              const float* __restrict__ aS, const float* __restrict__ aD,
                                              const unsigned short* __restrict__ h2b, const float* __restrict__ b2,
                                              const float* __restrict__ g2, const float* __restrict__ be2,
                                              const float* __restrict__ m2, const float* __restrict__ v2,
                                              float* __restrict__ emb) {
  int wave = threadIdx.x >> 6;
  int lane = threadIdx.x & 63;
  int d = blockIdx.x * 4 + wave;
  if (d >= N_NODES) return;
  float ad = aD[d];
  int s0 = row_ptr[d], s1 = row_ptr[d + 1];
  float denom = 0.f, acc = 0.f;
  int i = s0;
  int iend4 = s0 + ((s1 - s0) & ~3);
  for (; i < iend4; i += 4) {
    int cv = col[i + (lane & 3)];
    int sa = __builtin_amdgcn_readfirstlane(__shfl(cv, 0));
    int sb = __builtin_amdgcn_readfirstlane(__shfl(cv, 1));
    int sc = __builtin_amdgcn_readfirstlane(__shfl(cv, 2));
    int sd = __builtin_amdgcn_readfirstlane(__shfl(cv, 3));
    float ea = aS[sa];
    float eb = aS[sb];
    float ec = aS[sc];
    float ed = aS[sd];
    unsigned short ha = h2b[((size_t)sa << 6) + lane];
    unsigned short hb = h2b[((size_t)sb << 6) + lane];
    unsigned short hc = h2b[((size_t)sc << 6) + lane];
    unsigned short hd = h2b[((size_t)sd << 6) + lane];
    float wa = __expf(fminf(leaky(ea + ad), 80.f));
    float wb = __expf(fminf(leaky(eb + ad), 80.f));
    float wc = __expf(fminf(leaky(ec + ad), 80.f));
    float wd = __expf(fminf(leaky(ed + ad), 80.f));
    denom += (wa + wb) + (wc + wd);
    acc += wa * bf2f(ha) + wb * bf2f(hb) + wc * bf2f(hc) + wd * bf2f(hd);
  }
  for (; i < s1; i++) {
    int s = __builtin_amdgcn_readfirstlane(col[i]);
    float e = aS[s];
    unsigned short hv = h2b[((size_t)s << 6) + lane];
    float w = __expf(fminf(leaky(e + ad), 80.f));
    denom += w;
    acc += w * bf2f(hv);
  }
  float o = acc / (denom + 1e-16f) + b2[lane];
  o = (o - m2[lane]) * rsqrtf(v2[lane] + BN_EPS) * g2[lane] + be2[lane];
  emb[(size_t)d * HID + lane] = elu_f(o);
}

// ---------------- pooling partials ----------------
__global__ void __launch_bounds__(256) k_pool(const float* __restrict__ emb, float* __restrict__ psum,
                                              float* __restrict__ pmax) {
  __shared__ float ss[4][64], sm[4][64];
  int t = threadIdx.x;
  int c = t & 63, rg = t >> 6;
  float s = 0.f, m = -INFINITY;
  for (int n = blockIdx.x * 4 + rg; n < N_NODES; n += gridDim.x * 4) {
    float v = emb[(size_t)n * HID + c];
    s += v; m = fmaxf(m, v);
  }
  ss[rg][c] = s; sm[rg][c] = m;
  __syncthreads();
  if (t < 64) {
    psum[blockIdx.x * 64 + t] = ss[0][t] + ss[1][t] + ss[2][t] + ss[3][t];
    pmax[blockIdx.x * 64 + t] = fmaxf(fmaxf(sm[0][t], sm[1][t]), fmaxf(sm[2][t], sm[3][t]));
  }
}

// ---------------- final reduce + classifier ----------------
__global__ void __launch_bounds__(256) k_final(const float* __restrict__ psum, const float* __restrict__ pmax,
                                               const float* __restrict__ emb, const int* __restrict__ rootp,
                                               const float* __restrict__ cg1w, const float* __restrict__ cg1b,
                                               const float* __restrict__ cbng, const float* __restrict__ cbnb,
                                               const float* __restrict__ cbnm, const float* __restrict__ cbnv,
                                               const float* __restrict__ cg2w, const float* __restrict__ cg2b,
                                               const float* __restrict__ cg3w, const float* __restrict__ cg3b,
                                               float* __restrict__ out) {
  __shared__ float ss[4][64], sm[4][64];
  __shared__ float g[192], t1[64], t2[32];
  int t = threadIdx.x;
  int c = t & 63, q = t >> 6;
  float s = 0.f, m = -INFINITY;
  for (int b = q; b < 256; b += 4) {
    s += psum[b * 64 + c];
    m = fmaxf(m, pmax[b * 64 + c]);
  }
  ss[q][c] = s; sm[q][c] = m;
  __syncthreads();
  if (t < 64) {
    float tot = ss[0][t] + ss[1][t] + ss[2][t] + ss[3][t];
    float mx = fmaxf(fmaxf(sm[0][t], sm[1][t]), fmaxf(sm[2][t], sm[3][t]));
    int root = rootp[0];
    if (root > N_NODES - 1) root = N_NODES - 1;
    if (root < 0) root = 0;
    g[t] = tot / (float)N_NODES;
    g[64 + t] = mx;
    g[128 + t] = emb[(size_t)root * HID + t];
  }
  __syncthreads();
  if (t < 64) {
    float o = cg1b[t];
    for (int i = 0; i < 192; i++) o += g[i] * cg1w[i * 64 + t];
    o = (o - cbnm[t]) * rsqrtf(cbnv[t] + BN_EPS) * cbng[t] + cbnb[t];
    t1[t] = o > 0.f ? o : 0.f;
  }
  __syncthreads();
  if (t < 32) {
    float o = cg2b[t];
    for (int i = 0; i < 64; i++) o += t1[i] * cg2w[i * 32 + t];
    t2[t] = o > 0.f ? o : 0.f;
  }
  __syncthreads();
  if (t == 0) {
    float o = cg3b[0];
    for (int i = 0; i < 32; i++) o += t2[i] * cg3w[i];
    out[0] = o;
  }
}

extern "C" void kernel_launch(void* const* d_in, const int* in_sizes, int n_in,
                              void* d_out, int out_size, void* d_ws, size_t ws_size,
                              hipStream_t stream) {
  const float* x     = (const float*)d_in[0];
  const int*   edge  = (const int*)d_in[1];
  const int*   root  = (const int*)d_in[2];
  const float* W1    = (const float*)d_in[3];
  const float* attS1 = (const float*)d_in[4];
  const float* attD1 = (const float*)d_in[5];
  const float* b1    = (const float*)d_in[6];
  const float* W2    = (const float*)d_in[7];
  const float* attS2 = (const float*)d_in[8];
  const float* attD2 = (const float*)d_in[9];
  const float* b2    = (const float*)d_in[10];
  const float* bn1g  = (const float*)d_in[11];
  const float* bn1b  = (const float*)d_in[12];
  const float* bn1m  = (const float*)d_in[13];
  const float* bn1v  = (const float*)d_in[14];
  const float* bn2g  = (const float*)d_in[15];
  const float* bn2b  = (const float*)d_in[16];
  const float* bn2m  = (const float*)d_in[17];
  const float* bn2v  = (const float*)d_in[18];
  const float* cg1w  = (const float*)d_in[19];
  const float* cg1b  = (const float*)d_in[20];
  const float* cbng  = (const float*)d_in[21];
  const float* cbnb  = (const float*)d_in[22];
  const float* cbnm  = (const float*)d_in[23];
  const float* cbnv  = (const float*)d_in[24];
  const float* cg2w  = (const float*)d_in[25];
  const float* cg2b  = (const float*)d_in[26];
  const float* cg3w  = (const float*)d_in[27];
  const float* cg3b  = (const float*)d_in[28];

  // workspace arena (256B aligned blocks)
  char* ws = (char*)d_ws;
  size_t off = 0;
  auto carve = [&](size_t bytes) { char* p = ws + off; off += (bytes + 255) & ~(size_t)255; return p; };
  unsigned short* h1b = (unsigned short*)carve((size_t)N_NODES * C1 * 2);  // 51.2 MB
  unsigned short* hmb = (unsigned short*)carve((size_t)N_NODES * C1 * 2);  // 51.2 MB
  float* aS1     = (float*)carve((size_t)N_NODES * 4 * 4);
  float* aD1     = (float*)carve((size_t)N_NODES * 4 * 4);
  int*   deg     = (int*)  carve((size_t)N_NODES * 4);
  int*   row_ptr = (int*)  carve((size_t)(N_NODES + 1) * 4);
  int*   cursor  = (int*)  carve((size_t)N_NODES * 4);
  int*   col     = (int*)  carve((size_t)ETOT * 4);
  int*   part    = (int*)  carve(512);
  // layer-2 buffers alias regions that are dead by the time they're written:
  // h2b/aS2/aD2 live in h1b's region (dead after k_agg1 reads it);
  // emb/psum/pmax live in hmb's region (dead after k_gemm2 reads it).
  unsigned short* h2b = h1b;                           // N*64 bf16 = 12.8 MB < 51.2
  float* aS2  = (float*)(h1b + (size_t)N_NODES * HID); // N
  float* aD2  = aS2 + N_NODES;
  float* emb  = (float*)hmb;                           // N*64 f32 = 25.6 MB < 51.2
  float* psum = emb + (size_t)N_NODES * HID;           // 256*64
  float* pmax = psum + 256 * 64;

  // CSR build
  k_init_deg<<<(N_NODES + 255) / 256, 256, 0, stream>>>(deg);
  k_deg<<<(N_EDGES + 255) / 256, 256, 0, stream>>>(edge, deg);
  k_scan_part<<<NCHUNK, 256, 0, stream>>>(deg, part);
  k_scan_top<<<1, 64, 0, stream>>>(part, row_ptr);
  k_scan_down<<<NCHUNK, 256, 0, stream>>>(deg, part, row_ptr, cursor);
  k_fill<<<(ETOT + 255) / 256, 256, 0, stream>>>(edge, cursor, col);
  // layer 1
  k_gemm1<<<(N_NODES + 63) / 64, 256, 0, stream>>>(x, W1, attS1, attD1, h1b, aS1, aD1);
  k_agg1<<<(N_NODES + 3) / 4, 256, 0, stream>>>(row_ptr, col, aS1, aD1, h1b, b1, bn1g, bn1b, bn1m, bn1v, hmb);
  // layer 2
  k_gemm2<<<(N_NODES + 63) / 64, 256, 0, stream>>>(hmb, W2, attS2, attD2, h2b, aS2, aD2);
  k_agg2<<<(N_NODES + 3) / 4, 256, 0, stream>>>(row_ptr, col, aS2, aD2, h2b, b2, bn2g, bn2b, bn2m, bn2v, emb);
  // pooling + classifier
  k_pool<<<256, 256, 0, stream>>>(emb, psum, pmax);
  k_final<<<1, 256, 0, stream>>>(psum, pmax, emb, root, cg1w, cg1b, cbng, cbnb, cbnm, cbnv,
                                 cg2w, cg2b, cg3w, cg3b, (float*)d_out);
}

// Round 5
// 548.677 us; speedup vs baseline: 1.8754x; 1.1698x over previous
//
#include <hip/hip_runtime.h>

#define N_NODES 100000
#define N_EDGES 1600000
#define ETOT    1700000   // edges + self loops
#define IN_CH   128
#define C1      256       // HEADS*HID
#define HID     64
#define BN_EPS  1e-5f
#define SLOPE   0.2f
#define NCHUNK  98        // ceil(N/1024)

typedef __attribute__((ext_vector_type(8))) short s16x8;
typedef __attribute__((ext_vector_type(4))) float f32x4;
#define MFMA16(a, b, c) __builtin_amdgcn_mfma_f32_16x16x32_bf16(a, b, c, 0, 0, 0)

__device__ __forceinline__ float leaky(float x) { return fmaxf(x, SLOPE * x); }
__device__ __forceinline__ float elu_f(float x) { return x > 0.f ? x : __expf(x) - 1.f; }
__device__ __forceinline__ unsigned short f2bf(float f) {   // RNE fp32->bf16
  unsigned int b = __float_as_uint(f);
  return (unsigned short)((b + 0x7FFFu + ((b >> 16) & 1u)) >> 16);
}
__device__ __forceinline__ float bf2f(unsigned short u) {
  return __uint_as_float((unsigned int)u << 16);
}

// ---------------- CSR build ----------------
__global__ void __launch_bounds__(256) k_init_deg(int* __restrict__ deg) {
  int n = blockIdx.x * 256 + threadIdx.x;
  if (n < N_NODES) deg[n] = 1;  // self loop
}

__global__ void __launch_bounds__(256) k_deg(const int* __restrict__ edge, int* __restrict__ deg) {
  int i = blockIdx.x * 256 + threadIdx.x;
  if (i < N_EDGES) atomicAdd(&deg[edge[N_EDGES + i]], 1);
}

__global__ void __launch_bounds__(256) k_scan_part(const int* __restrict__ deg, int* __restrict__ part) {
  __shared__ int ls[256];
  int t = threadIdx.x;
  int base = blockIdx.x * 1024 + t * 4;
  int s = 0;
#pragma unroll
  for (int j = 0; j < 4; j++) if (base + j < N_NODES) s += deg[base + j];
  ls[t] = s;
  __syncthreads();
  for (int off = 128; off >= 1; off >>= 1) {
    if (t < off) ls[t] += ls[t + off];
    __syncthreads();
  }
  if (t == 0) part[blockIdx.x] = ls[0];
}

__global__ void k_scan_top(int* __restrict__ part, int* __restrict__ row_ptr) {
  if (threadIdx.x == 0 && blockIdx.x == 0) {
    int run = 0;
    for (int i = 0; i < NCHUNK; i++) { int t = part[i]; part[i] = run; run += t; }
    row_ptr[N_NODES] = run;   // == ETOT
  }
}

__global__ void __launch_bounds__(256) k_scan_down(const int* __restrict__ deg, const int* __restrict__ part,
                                                   int* __restrict__ row_ptr, int* __restrict__ cursor) {
  __shared__ int ls[256];
  int t = threadIdx.x;
  int base = blockIdx.x * 1024 + t * 4;
  int v[4];
#pragma unroll
  for (int j = 0; j < 4; j++) v[j] = (base + j < N_NODES) ? deg[base + j] : 0;
  int tsum = v[0] + v[1] + v[2] + v[3];
  ls[t] = tsum;
  __syncthreads();
  for (int off = 1; off < 256; off <<= 1) {
    int add = (t >= off) ? ls[t - off] : 0;
    __syncthreads();
    ls[t] += add;
    __syncthreads();
  }
  int excl = ls[t] - tsum + part[blockIdx.x];
#pragma unroll
  for (int j = 0; j < 4; j++) {
    int idx = base + j;
    if (idx < N_NODES) { row_ptr[idx] = excl; cursor[idx] = excl; }
    excl += v[j];
  }
}

__global__ void __launch_bounds__(256) k_fill(const int* __restrict__ edge, int* __restrict__ cursor,
                                              int* __restrict__ col) {
  int i = blockIdx.x * 256 + threadIdx.x;
  int s, d;
  if (i < N_EDGES) { s = edge[i]; d = edge[N_EDGES + i]; }
  else if (i < ETOT) { s = i - N_EDGES; d = s; }
  else return;
  int pos = atomicAdd(&cursor[d], 1);
  col[pos] = s;
}

// ---------------- weight prep: W1 [128][256] -> W1T bf16 [256][128]; W2 [256][64] -> W2T bf16 [64][256] ----------------
__global__ void __launch_bounds__(256) k_prep(const float* __restrict__ W1, const float* __restrict__ W2,
                                              unsigned short* __restrict__ W1T, unsigned short* __restrict__ W2T) {
  int i = blockIdx.x * 256 + threadIdx.x;
  if (i < IN_CH * C1) {
    int k = i >> 8, c = i & 255;
    W1T[c * IN_CH + k] = f2bf(W1[i]);
  }
  if (i < C1 * HID) {
    int k = i >> 6, c = i & 63;
    W2T[c * C1 + k] = f2bf(W2[i]);
  }
}

// ---------------- GEMM1 (MFMA bf16): h1 = x @ W1, fused att dots ----------------
// block = 64 rows x 256 cols; wave w owns col quadrant w*64..w*64+64 (== head w), all 64 rows.
__global__ void __launch_bounds__(256) k_gemm1(const float* __restrict__ x, const unsigned short* __restrict__ W1T,
                                               const float* __restrict__ attS, const float* __restrict__ attD,
                                               unsigned short* __restrict__ h1b, float* __restrict__ aS,
                                               float* __restrict__ aD) {
  __shared__ unsigned short As[64][IN_CH + 8];   // +8 pad -> <=2-way bank conflict on frag reads
  int tid = threadIdx.x;
  int w = tid >> 6, lane = tid & 63;
  int l15 = lane & 15, l4 = lane >> 4;
  int row0 = blockIdx.x * 64;
  // stage x tile as bf16
#pragma unroll
  for (int it = 0; it < 8; it++) {
    int idx = tid + it * 256;          // float4 chunk id, 2048 total
    int r = idx >> 5;
    int k4 = (idx & 31) * 4;
    int gr = row0 + r; if (gr >= N_NODES) gr = N_NODES - 1;
    float4 v = *(const float4*)(x + (size_t)gr * IN_CH + k4);
    ushort4 bvec;
    bvec.x = f2bf(v.x); bvec.y = f2bf(v.y); bvec.z = f2bf(v.z); bvec.w = f2bf(v.w);
    *(ushort4*)&As[r][k4] = bvec;
  }
  __syncthreads();
  f32x4 acc[4][4];                     // [mf][cf]
#pragma unroll
  for (int mf = 0; mf < 4; mf++)
#pragma unroll
    for (int cf = 0; cf < 4; cf++) acc[mf][cf] = (f32x4){0.f, 0.f, 0.f, 0.f};
#pragma unroll
  for (int ks = 0; ks < 4; ks++) {
    int koff = ks * 32 + l4 * 8;
    s16x8 a[4];
#pragma unroll
    for (int mf = 0; mf < 4; mf++) a[mf] = *(const s16x8*)&As[mf * 16 + l15][koff];
#pragma unroll
    for (int cf = 0; cf < 4; cf++) {
      s16x8 b = *(const s16x8*)(W1T + (size_t)(w * 64 + cf * 16 + l15) * IN_CH + koff);
#pragma unroll
      for (int mf = 0; mf < 4; mf++) acc[mf][cf] = MFMA16(a[mf], b, acc[mf][cf]);
    }
  }
  // epilogue: store h1b (cols w*64+cf*16+l15) + per-head att dots (head == w)
  float as_c[4], ad_c[4];
#pragma unroll
  for (int cf = 0; cf < 4; cf++) {
    as_c[cf] = attS[w * HID + cf * 16 + l15];
    ad_c[cf] = attD[w * HID + cf * 16 + l15];
  }
#pragma unroll
  for (int mf = 0; mf < 4; mf++) {
#pragma unroll
    for (int reg = 0; reg < 4; reg++) {
      int gr = row0 + mf * 16 + l4 * 4 + reg;
      bool ok = gr < N_NODES;
      float s = 0.f, dd = 0.f;
#pragma unroll
      for (int cf = 0; cf < 4; cf++) {
        float v = acc[mf][cf][reg];
        if (ok) h1b[(size_t)gr * C1 + w * 64 + cf * 16 + l15] = f2bf(v);
        s += v * as_c[cf];
        dd += v * ad_c[cf];
      }
#pragma unroll
      for (int m = 1; m <= 8; m <<= 1) { s += __shfl_xor(s, m, 64); dd += __shfl_xor(dd, m, 64); }
      if (ok && l15 == 0) {
        aS[(size_t)gr * 4 + w] = s;
        aD[(size_t)gr * 4 + w] = dd;
      }
    }
  }
}

// ---------------- layer-1 aggregate: 8-deep pipelined gather, scalar bases, bf16 in/out ----------------
__global__ void __launch_bounds__(256) k_agg1(const int* __restrict__ row_ptr, const int* __restrict__ col,
                                              const float* __restrict__ aS, const float* __restrict__ aD,
                                              const unsigned short* __restrict__ h1b, const float* __restrict__ b1,
                                              const float* __restrict__ g1, const float* __restrict__ be1,
                                              const float* __restrict__ m1, const float* __restrict__ v1,
                                              unsigned short* __restrict__ hmb) {
  int wave = threadIdx.x >> 6;
  int lane = threadIdx.x & 63;
  int d = blockIdx.x * 4 + wave;
  if (d >= N_NODES) return;
  int head = lane >> 4;
  float ad = aD[d * 4 + head];
  int s0 = row_ptr[d], s1 = row_ptr[d + 1];
  float denom = 0.f;
  float4 acc = {0.f, 0.f, 0.f, 0.f};
  int c0 = lane * 4;
  int i = s0;
  int iend8 = s0 + ((s1 - s0) & ~7);
  for (; i < iend8; i += 8) {
    int cv = col[i + (lane & 7)];      // one 32B segment holds the 8 ids
    int sid[8];
#pragma unroll
    for (int j = 0; j < 8; j++) sid[j] = __builtin_amdgcn_readfirstlane(__shfl(cv, j));
    float e[8];
#pragma unroll
    for (int j = 0; j < 8; j++) e[j] = aS[(sid[j] << 2) + head];
    ushort4 h[8];
#pragma unroll
    for (int j = 0; j < 8; j++) h[j] = *(const ushort4*)(h1b + ((size_t)sid[j] << 8) + c0);
    float wv[8];
#pragma unroll
    for (int j = 0; j < 8; j++) wv[j] = __expf(fminf(leaky(e[j] + ad), 80.f));
#pragma unroll
    for (int j = 0; j < 8; j++) {
      denom += wv[j];
      acc.x += wv[j] * bf2f(h[j].x);
      acc.y += wv[j] * bf2f(h[j].y);
      acc.z += wv[j] * bf2f(h[j].z);
      acc.w += wv[j] * bf2f(h[j].w);
    }
  }
  for (; i < s1; i++) {
    int s = __builtin_amdgcn_readfirstlane(col[i]);
    float e = aS[(s << 2) + head];
    ushort4 hv = *(const ushort4*)(h1b + ((size_t)s << 8) + c0);
    float wv = __expf(fminf(leaky(e + ad), 80.f));
    denom += wv;
    acc.x += wv * bf2f(hv.x);
    acc.y += wv * bf2f(hv.y);
    acc.z += wv * bf2f(hv.z);
    acc.w += wv * bf2f(hv.w);
  }
  float inv = 1.f / (denom + 1e-16f);
  float4 bb = *(const float4*)(b1 + c0);
  float4 gg = *(const float4*)(g1 + c0);
  float4 be = *(const float4*)(be1 + c0);
  float4 mm = *(const float4*)(m1 + c0);
  float4 vv = *(const float4*)(v1 + c0);
  ushort4 o;
  o.x = f2bf(elu_f((acc.x * inv + bb.x - mm.x) * rsqrtf(vv.x + BN_EPS) * gg.x + be.x));
  o.y = f2bf(elu_f((acc.y * inv + bb.y - mm.y) * rsqrtf(vv.y + BN_EPS) * gg.y + be.y));
  o.z = f2bf(elu_f((acc.z * inv + bb.z - mm.z) * rsqrtf(vv.z + BN_EPS) * gg.z + be.z));
  o.w = f2bf(elu_f((acc.w * inv + bb.w - mm.w) * rsqrtf(vv.w + BN_EPS) * gg.w + be.w));
  *(ushort4*)(hmb + (size_t)d * C1 + c0) = o;
}

// ---------------- GEMM2 (MFMA bf16): h2 = hm @ W2, fused att dots ----------------
// block = 64 rows x 64 cols; wave w owns row quadrant w*16..w*16+16, all 64 cols.
__global__ void __launch_bounds__(256) k_gemm2(const unsigned short* __restrict__ hmb, const unsigned short* __restrict__ W2T,
                                               const float* __restrict__ attS, const float* __restrict__ attD,
                                               unsigned short* __restrict__ h2b, float* __restrict__ aS,
                                               float* __restrict__ aD) {
  __shared__ unsigned short As[64][C1 + 8];     // 33.8 KB
  int tid = threadIdx.x;
  int w = tid >> 6, lane = tid & 63;
  int l15 = lane & 15, l4 = lane >> 4;
  int row0 = blockIdx.x * 64;
#pragma unroll
  for (int it = 0; it < 8; it++) {
    int idx = tid + it * 256;          // uint4 chunk (8 bf16), 2048 total
    int r = idx >> 5;
    int k8 = (idx & 31) * 8;
    int gr = row0 + r; if (gr >= N_NODES) gr = N_NODES - 1;
    *(uint4*)&As[r][k8] = *(const uint4*)(hmb + (size_t)gr * C1 + k8);
  }
  __syncthreads();
  f32x4 acc[4];                        // [cf]
#pragma unroll
  for (int cf = 0; cf < 4; cf++) acc[cf] = (f32x4){0.f, 0.f, 0.f, 0.f};
#pragma unroll
  for (int ks = 0; ks < 8; ks++) {
    int koff = ks * 32 + l4 * 8;
    s16x8 a = *(const s16x8*)&As[w * 16 + l15][koff];
#pragma unroll
    for (int cf = 0; cf < 4; cf++) {
      s16x8 b = *(const s16x8*)(W2T + (size_t)(cf * 16 + l15) * C1 + koff);
      acc[cf] = MFMA16(a, b, acc[cf]);
    }
  }
  float as_c[4], ad_c[4];
#pragma unroll
  for (int cf = 0; cf < 4; cf++) {
    as_c[cf] = attS[cf * 16 + l15];
    ad_c[cf] = attD[cf * 16 + l15];
  }
#pragma unroll
  for (int reg = 0; reg < 4; reg++) {
    int gr = row0 + w * 16 + l4 * 4 + reg;
    bool ok = gr < N_NODES;
    float s = 0.f, dd = 0.f;
#pragma unroll
    for (int cf = 0; cf < 4; cf++) {
      float v = acc[cf][reg];
      if (ok) h2b[(size_t)gr * HID + cf * 16 + l15] = f2bf(v);
      s += v * as_c[cf];
      dd += v * ad_c[cf];
    }
#pragma unroll
    for (int m = 1; m <= 8; m <<= 1) { s += __shfl_xor(s, m, 64); dd += __shfl_xor(dd, m, 64); }
    if (ok && l15 == 0) { aS[gr] = s; aD[gr] = dd; }
  }
}

// ---------------- layer-2 aggregate: 8-deep pipelined gather, scalar bases ----------------
__global__ void __launch_bounds__(256) k_agg2(const int* __restrict__ row_ptr, const int* __restrict__ col,
                                              const float* __restrict__ aS, const float* __restrict__ aD,
                                              const unsigned short* __restrict__ h2b, const float* __restrict__ b2,
                                              const float* __restrict__ g2, const float* __restrict__ be2,
                                              const float* __restrict__ m2, const float* __restrict__ v2,
                                              float* __restrict__ emb) {
  int wave = threadIdx.x >> 6;
  int lane = threadIdx.x & 63;
  int d = blockIdx.x * 4 + wave;
  if (d >= N_NODES) return;
  float ad = aD[d];
  int s0 = row_ptr[d], s1 = row_ptr[d + 1];
  float denom = 0.f, acc = 0.f;
  int i = s0;
  int iend8 = s0 + ((s1 - s0) & ~7);
  for (; i < iend8; i += 8) {
    int cv = col[i + (lane & 7)];
    int sid[8];
#pragma unroll
    for (int j = 0; j < 8; j++) sid[j] = __builtin_amdgcn_readfirstlane(__shfl(cv, j));
    float e[8];
#pragma unroll
    for (int j = 0; j < 8; j++) e[j] = aS[sid[j]];
    unsigned short h[8];
#pragma unroll
    for (int j = 0; j < 8; j++) h[j] = h2b[((size_t)sid[j] << 6) + lane];
    float wv[8];
#pragma unroll
    for (int j = 0; j < 8; j++) wv[j] = __expf(fminf(leaky(e[j] + ad), 80.f));
#pragma unroll
    for (int j = 0; j < 8; j++) {
      denom += wv[j];
      acc += wv[j] * bf2f(h[j]);
    }
  }
  for (; i < s1; i++) {
    int s = __builtin_amdgcn_readfirstlane(col[i]);
    float e = aS[s];
    unsigned short hv = h2b[((size_t)s << 6) + lane];
    float wv = __expf(fminf(leaky(e + ad), 80.f));
    denom += wv;
    acc += wv * bf2f(hv);
  }
  float o = acc / (denom + 1e-16f) + b2[lane];
  o = (o - m2[lane]) * rsqrtf(v2[lane] + BN_EPS) * g2[lane] + be2[lane];
  emb[(size_t)d * HID + lane] = elu_f(o);
}

// ---------------- pooling partials ----------------
__global__ void __launch_bounds__(256) k_pool(const float* __restrict__ emb, float* __restrict__ psum,
                                              float* __restrict__ pmax) {
  __shared__ float ss[4][64], sm[4][64];
  int t = threadIdx.x;
  int c = t & 63, rg = t >> 6;
  float s = 0.f, m = -INFINITY;
  for (int n = blockIdx.x * 4 + rg; n < N_NODES; n += gridDim.x * 4) {
    float v = emb[(size_t)n * HID + c];
    s += v; m = fmaxf(m, v);
  }
  ss[rg][c] = s; sm[rg][c] = m;
  __syncthreads();
  if (t < 64) {
    psum[blockIdx.x * 64 + t] = ss[0][t] + ss[1][t] + ss[2][t] + ss[3][t];
    pmax[blockIdx.x * 64 + t] = fmaxf(fmaxf(sm[0][t], sm[1][t]), fmaxf(sm[2][t], sm[3][t]));
  }
}

// ---------------- final reduce + classifier ----------------
__global__ void __launch_bounds__(256) k_final(const float* __restrict__ psum, const float* __restrict__ pmax,
                                               const float* __restrict__ emb, const int* __restrict__ rootp,
                                               const float* __restrict__ cg1w, const float* __restrict__ cg1b,
                                               const float* __restrict__ cbng, const float* __restrict__ cbnb,
                                               const float* __restrict__ cbnm, const float* __restrict__ cbnv,
                                               const float* __restrict__ cg2w, const float* __restrict__ cg2b,
                                               const float* __restrict__ cg3w, const float* __restrict__ cg3b,
                                               float* __restrict__ out) {
  __shared__ float ss[4][64], sm[4][64];
  __shared__ float g[192], t1[64], t2[32];
  int t = threadIdx.x;
  int c = t & 63, q = t >> 6;
  float s = 0.f, m = -INFINITY;
  for (int b = q; b < 256; b += 4) {
    s += psum[b * 64 + c];
    m = fmaxf(m, pmax[b * 64 + c]);
  }
  ss[q][c] = s; sm[q][c] = m;
  __syncthreads();
  if (t < 64) {
    float tot = ss[0][t] + ss[1][t] + ss[2][t] + ss[3][t];
    float mx = fmaxf(fmaxf(sm[0][t], sm[1][t]), fmaxf(sm[2][t], sm[3][t]));
    int root = rootp[0];
    if (root > N_NODES - 1) root = N_NODES - 1;
    if (root < 0) root = 0;
    g[t] = tot / (float)N_NODES;
    g[64 + t] = mx;
    g[128 + t] = emb[(size_t)root * HID + t];
  }
  __syncthreads();
  if (t < 64) {
    float o = cg1b[t];
    for (int i = 0; i < 192; i++) o += g[i] * cg1w[i * 64 + t];
    o = (o - cbnm[t]) * rsqrtf(cbnv[t] + BN_EPS) * cbng[t] + cbnb[t];
    t1[t] = o > 0.f ? o : 0.f;
  }
  __syncthreads();
  if (t < 32) {
    float o = cg2b[t];
    for (int i = 0; i < 64; i++) o += t1[i] * cg2w[i * 32 + t];
    t2[t] = o > 0.f ? o : 0.f;
  }
  __syncthreads();
  if (t == 0) {
    float o = cg3b[0];
    for (int i = 0; i < 32; i++) o += t2[i] * cg3w[i];
    out[0] = o;
  }
}

extern "C" void kernel_launch(void* const* d_in, const int* in_sizes, int n_in,
                              void* d_out, int out_size, void* d_ws, size_t ws_size,
                              hipStream_t stream) {
  const float* x     = (const float*)d_in[0];
  const int*   edge  = (const int*)d_in[1];
  const int*   root  = (const int*)d_in[2];
  const float* W1    = (const float*)d_in[3];
  const float* attS1 = (const float*)d_in[4];
  const float* attD1 = (const float*)d_in[5];
  const float* b1    = (const float*)d_in[6];
  const float* W2    = (const float*)d_in[7];
  const float* attS2 = (const float*)d_in[8];
  const float* attD2 = (const float*)d_in[9];
  const float* b2    = (const float*)d_in[10];
  const float* bn1g  = (const float*)d_in[11];
  const float* bn1b  = (const float*)d_in[12];
  const float* bn1m  = (const float*)d_in[13];
  const float* bn1v  = (const float*)d_in[14];
  const float* bn2g  = (const float*)d_in[15];
  const float* bn2b  = (const float*)d_in[16];
  const float* bn2m  = (const float*)d_in[17];
  const float* bn2v  = (const float*)d_in[18];
  const float* cg1w  = (const float*)d_in[19];
  const float* cg1b  = (const float*)d_in[20];
  const float* cbng  = (const float*)d_in[21];
  const float* cbnb  = (const float*)d_in[22];
  const float* cbnm  = (const float*)d_in[23];
  const float* cbnv  = (const float*)d_in[24];
  const float* cg2w  = (const float*)d_in[25];
  const float* cg2b  = (const float*)d_in[26];
  const float* cg3w  = (const float*)d_in[27];
  const float* cg3b  = (const float*)d_in[28];

  // workspace arena (256B aligned blocks)
  char* ws = (char*)d_ws;
  size_t off = 0;
  auto carve = [&](size_t bytes) { char* p = ws + off; off += (bytes + 255) & ~(size_t)255; return p; };
  unsigned short* h1b = (unsigned short*)carve((size_t)N_NODES * C1 * 2);  // 51.2 MB
  unsigned short* hmb = (unsigned short*)carve((size_t)N_NODES * C1 * 2);  // 51.2 MB
  float* aS1     = (float*)carve((size_t)N_NODES * 4 * 4);
  float* aD1     = (float*)carve((size_t)N_NODES * 4 * 4);
  int*   deg     = (int*)  carve((size_t)N_NODES * 4);
  int*   row_ptr = (int*)  carve((size_t)(N_NODES + 1) * 4);
  int*   cursor  = (int*)  carve((size_t)N_NODES * 4);
  int*   col     = (int*)  carve((size_t)ETOT * 4);
  int*   part    = (int*)  carve(512);
  unsigned short* W1T = (unsigned short*)carve((size_t)IN_CH * C1 * 2);    // 64 KB
  unsigned short* W2T = (unsigned short*)carve((size_t)C1 * HID * 2);      // 32 KB
  // layer-2 buffers alias regions that are dead by the time they're written:
  // h2b/aS2/aD2 live in h1b's region (dead after k_agg1 reads it);
  // emb/psum/pmax live in hmb's region (dead after k_gemm2 reads it).
  unsigned short* h2b = h1b;                           // N*64 bf16 = 12.8 MB < 51.2
  float* aS2  = (float*)(h1b + (size_t)N_NODES * HID); // N
  float* aD2  = aS2 + N_NODES;
  float* emb  = (float*)hmb;                           // N*64 f32 = 25.6 MB < 51.2
  float* psum = emb + (size_t)N_NODES * HID;           // 256*64
  float* pmax = psum + 256 * 64;

  // CSR build + weight prep
  k_init_deg<<<(N_NODES + 255) / 256, 256, 0, stream>>>(deg);
  k_deg<<<(N_EDGES + 255) / 256, 256, 0, stream>>>(edge, deg);
  k_prep<<<(IN_CH * C1 + 255) / 256, 256, 0, stream>>>(W1, W2, W1T, W2T);
  k_scan_part<<<NCHUNK, 256, 0, stream>>>(deg, part);
  k_scan_top<<<1, 64, 0, stream>>>(part, row_ptr);
  k_scan_down<<<NCHUNK, 256, 0, stream>>>(deg, part, row_ptr, cursor);
  k_fill<<<(ETOT + 255) / 256, 256, 0, stream>>>(edge, cursor, col);
  // layer 1
  k_gemm1<<<(N_NODES + 63) / 64, 256, 0, stream>>>(x, W1T, attS1, attD1, h1b, aS1, aD1);
  k_agg1<<<(N_NODES + 3) / 4, 256, 0, stream>>>(row_ptr, col, aS1, aD1, h1b, b1, bn1g, bn1b, bn1m, bn1v, hmb);
  // layer 2
  k_gemm2<<<(N_NODES + 63) / 64, 256, 0, stream>>>(hmb, W2T, attS2, attD2, h2b, aS2, aD2);
  k_agg2<<<(N_NODES + 3) / 4, 256, 0, stream>>>(row_ptr, col, aS2, aD2, h2b, b2, bn2g, bn2b, bn2m, bn2v, emb);
  // pooling + classifier
  k_pool<<<256, 256, 0, stream>>>(emb, psum, pmax);
  k_final<<<1, 256, 0, stream>>>(psum, pmax, emb, root, cg1w, cg1b, cbng, cbnb, cbnm, cbnv,
                                 cg2w, cg2b, cg3w, cg3b, (float*)d_out);
}

// Round 6
// 502.944 us; speedup vs baseline: 2.0459x; 1.0909x over previous
//
#include <hip/hip_runtime.h>

#define N_NODES 100000
#define N_EDGES 1600000
#define ETOT    1700000   // edges + self loops
#define IN_CH   128
#define C1      256       // HEADS*HID
#define HID     64
#define BN_EPS  1e-5f
#define SLOPE   0.2f
#define NCHUNK  98        // ceil(N/1024)
#define FILL_PH 8
#define PH_NODES 12500    // N_NODES / FILL_PH

typedef __attribute__((ext_vector_type(8))) short s16x8;
typedef __attribute__((ext_vector_type(4))) float f32x4;
#define MFMA16(a, b, c) __builtin_amdgcn_mfma_f32_16x16x32_bf16(a, b, c, 0, 0, 0)

__device__ __forceinline__ float leaky(float x) { return fmaxf(x, SLOPE * x); }
__device__ __forceinline__ float elu_f(float x) { return x > 0.f ? x : __expf(x) - 1.f; }
__device__ __forceinline__ unsigned short f2bf(float f) {   // RNE fp32->bf16
  unsigned int b = __float_as_uint(f);
  return (unsigned short)((b + 0x7FFFu + ((b >> 16) & 1u)) >> 16);
}
__device__ __forceinline__ float bf2f(unsigned short u) {
  return __uint_as_float((unsigned int)u << 16);
}

// ---------------- CSR build ----------------
__global__ void __launch_bounds__(256) k_init_deg(int* __restrict__ deg) {
  int n = blockIdx.x * 256 + threadIdx.x;
  if (n < N_NODES) deg[n] = 1;  // self loop
}

// dst-range phased degree count: blockIdx-major phases confine the atomic
// target range to 50KB so every XCD L2 retains it (kills partial-line thrash).
__global__ void __launch_bounds__(256) k_deg_ph(const int* __restrict__ edge, int* __restrict__ deg) {
  int bpp = (N_EDGES + 1023) >> 10;      // blocks per phase, 4 edges/thread
  int ph = blockIdx.x / bpp;
  int lo = ph * PH_NODES, hi = lo + PH_NODES;
  int i0 = (blockIdx.x % bpp) * 1024 + threadIdx.x * 4;
  if (i0 >= N_EDGES) return;
  if (i0 + 3 < N_EDGES) {
    int4 dv = *(const int4*)(edge + N_EDGES + i0);
    if (dv.x >= lo && dv.x < hi) atomicAdd(&deg[dv.x], 1);
    if (dv.y >= lo && dv.y < hi) atomicAdd(&deg[dv.y], 1);
    if (dv.z >= lo && dv.z < hi) atomicAdd(&deg[dv.z], 1);
    if (dv.w >= lo && dv.w < hi) atomicAdd(&deg[dv.w], 1);
  } else {
    for (int j = 0; j < 4 && i0 + j < N_EDGES; j++) {
      int d = edge[N_EDGES + i0 + j];
      if (d >= lo && d < hi) atomicAdd(&deg[d], 1);
    }
  }
}

__global__ void __launch_bounds__(256) k_scan_part(const int* __restrict__ deg, int* __restrict__ part) {
  __shared__ int ls[256];
  int t = threadIdx.x;
  int base = blockIdx.x * 1024 + t * 4;
  int s = 0;
#pragma unroll
  for (int j = 0; j < 4; j++) if (base + j < N_NODES) s += deg[base + j];
  ls[t] = s;
  __syncthreads();
  for (int off = 128; off >= 1; off >>= 1) {
    if (t < off) ls[t] += ls[t + off];
    __syncthreads();
  }
  if (t == 0) part[blockIdx.x] = ls[0];
}

__global__ void k_scan_top(int* __restrict__ part, int* __restrict__ row_ptr) {
  if (threadIdx.x == 0 && blockIdx.x == 0) {
    int run = 0;
    for (int i = 0; i < NCHUNK; i++) { int t = part[i]; part[i] = run; run += t; }
    row_ptr[N_NODES] = run;   // == ETOT
  }
}

__global__ void __launch_bounds__(256) k_scan_down(const int* __restrict__ deg, const int* __restrict__ part,
                                                   int* __restrict__ row_ptr, int* __restrict__ cursor) {
  __shared__ int ls[256];
  int t = threadIdx.x;
  int base = blockIdx.x * 1024 + t * 4;
  int v[4];
#pragma unroll
  for (int j = 0; j < 4; j++) v[j] = (base + j < N_NODES) ? deg[base + j] : 0;
  int tsum = v[0] + v[1] + v[2] + v[3];
  ls[t] = tsum;
  __syncthreads();
  for (int off = 1; off < 256; off <<= 1) {
    int add = (t >= off) ? ls[t - off] : 0;
    __syncthreads();
    ls[t] += add;
    __syncthreads();
  }
  int excl = ls[t] - tsum + part[blockIdx.x];
#pragma unroll
  for (int j = 0; j < 4; j++) {
    int idx = base + j;
    if (idx < N_NODES) { row_ptr[idx] = excl; cursor[idx] = excl; }
    excl += v[j];
  }
}

// dst-range phased fill: per phase the col scatter range is ~850KB -> L2-resident
// in every XCD, lines accumulate all writes before one full-line writeback.
__global__ void __launch_bounds__(256) k_fill_ph(const int* __restrict__ edge, int* __restrict__ cursor,
                                                 int* __restrict__ col) {
  int bpp = (ETOT + 255) >> 8;           // blocks per phase
  int ph = blockIdx.x / bpp;
  int lo = ph * PH_NODES, hi = lo + PH_NODES;
  int i = (blockIdx.x % bpp) * 256 + threadIdx.x;
  if (i >= ETOT) return;
  int d = (i < N_EDGES) ? edge[N_EDGES + i] : (i - N_EDGES);
  if (d < lo || d >= hi) return;
  int s = (i < N_EDGES) ? edge[i] : d;
  int pos = atomicAdd(&cursor[d], 1);
  col[pos] = s;
}

// ---------------- weight prep: W1 [128][256] -> W1T bf16 [256][128]; W2 [256][64] -> W2T bf16 [64][256] ----------------
__global__ void __launch_bounds__(256) k_prep(const float* __restrict__ W1, const float* __restrict__ W2,
                                              unsigned short* __restrict__ W1T, unsigned short* __restrict__ W2T) {
  int i = blockIdx.x * 256 + threadIdx.x;
  if (i < IN_CH * C1) {
    int k = i >> 8, c = i & 255;
    W1T[c * IN_CH + k] = f2bf(W1[i]);
  }
  if (i < C1 * HID) {
    int k = i >> 6, c = i & 63;
    W2T[c * C1 + k] = f2bf(W2[i]);
  }
}

// ---------------- GEMM1 (MFMA bf16): h1 = x @ W1, fused att dots ----------------
__global__ void __launch_bounds__(256) k_gemm1(const float* __restrict__ x, const unsigned short* __restrict__ W1T,
                                               const float* __restrict__ attS, const float* __restrict__ attD,
                                               unsigned short* __restrict__ h1b, float* __restrict__ aS,
                                               float* __restrict__ aD) {
  __shared__ unsigned short As[64][IN_CH + 8];   // +8 pad -> <=2-way bank conflict on frag reads
  int tid = threadIdx.x;
  int w = tid >> 6, lane = tid & 63;
  int l15 = lane & 15, l4 = lane >> 4;
  int row0 = blockIdx.x * 64;
#pragma unroll
  for (int it = 0; it < 8; it++) {
    int idx = tid + it * 256;          // float4 chunk id, 2048 total
    int r = idx >> 5;
    int k4 = (idx & 31) * 4;
    int gr = row0 + r; if (gr >= N_NODES) gr = N_NODES - 1;
    float4 v = *(const float4*)(x + (size_t)gr * IN_CH + k4);
    ushort4 bvec;
    bvec.x = f2bf(v.x); bvec.y = f2bf(v.y); bvec.z = f2bf(v.z); bvec.w = f2bf(v.w);
    *(ushort4*)&As[r][k4] = bvec;
  }
  __syncthreads();
  f32x4 acc[4][4];                     // [mf][cf]
#pragma unroll
  for (int mf = 0; mf < 4; mf++)
#pragma unroll
    for (int cf = 0; cf < 4; cf++) acc[mf][cf] = (f32x4){0.f, 0.f, 0.f, 0.f};
#pragma unroll
  for (int ks = 0; ks < 4; ks++) {
    int koff = ks * 32 + l4 * 8;
    s16x8 a[4];
#pragma unroll
    for (int mf = 0; mf < 4; mf++) a[mf] = *(const s16x8*)&As[mf * 16 + l15][koff];
#pragma unroll
    for (int cf = 0; cf < 4; cf++) {
      s16x8 b = *(const s16x8*)(W1T + (size_t)(w * 64 + cf * 16 + l15) * IN_CH + koff);
#pragma unroll
      for (int mf = 0; mf < 4; mf++) acc[mf][cf] = MFMA16(a[mf], b, acc[mf][cf]);
    }
  }
  float as_c[4], ad_c[4];
#pragma unroll
  for (int cf = 0; cf < 4; cf++) {
    as_c[cf] = attS[w * HID + cf * 16 + l15];
    ad_c[cf] = attD[w * HID + cf * 16 + l15];
  }
#pragma unroll
  for (int mf = 0; mf < 4; mf++) {
#pragma unroll
    for (int reg = 0; reg < 4; reg++) {
      int gr = row0 + mf * 16 + l4 * 4 + reg;
      bool ok = gr < N_NODES;
      float s = 0.f, dd = 0.f;
#pragma unroll
      for (int cf = 0; cf < 4; cf++) {
        float v = acc[mf][cf][reg];
        if (ok) h1b[(size_t)gr * C1 + w * 64 + cf * 16 + l15] = f2bf(v);
        s += v * as_c[cf];
        dd += v * ad_c[cf];
      }
#pragma unroll
      for (int m = 1; m <= 8; m <<= 1) { s += __shfl_xor(s, m, 64); dd += __shfl_xor(dd, m, 64); }
      if (ok && l15 == 0) {
        aS[(size_t)gr * 4 + w] = s;
        aD[(size_t)gr * 4 + w] = dd;
      }
    }
  }
}

// ---------------- layer-1 aggregate: 8-deep pipelined gather, scalar bases, bf16 in/out ----------------
__global__ void __launch_bounds__(256) k_agg1(const int* __restrict__ row_ptr, const int* __restrict__ col,
                                              const float* __restrict__ aS, const float* __restrict__ aD,
                                              const unsigned short* __restrict__ h1b, const float* __restrict__ b1,
                                              const float* __restrict__ g1, const float* __restrict__ be1,
                                              const float* __restrict__ m1, const float* __restrict__ v1,
                                              unsigned short* __restrict__ hmb) {
  int wave = threadIdx.x >> 6;
  int lane = threadIdx.x & 63;
  int d = blockIdx.x * 4 + wave;
  if (d >= N_NODES) return;
  int head = lane >> 4;
  float ad = aD[d * 4 + head];
  int s0 = row_ptr[d], s1 = row_ptr[d + 1];
  float denom = 0.f;
  float4 acc = {0.f, 0.f, 0.f, 0.f};
  int c0 = lane * 4;
  int i = s0;
  int iend8 = s0 + ((s1 - s0) & ~7);
  for (; i < iend8; i += 8) {
    int cv = col[i + (lane & 7)];      // one 32B segment holds the 8 ids
    int sid[8];
#pragma unroll
    for (int j = 0; j < 8; j++) sid[j] = __builtin_amdgcn_readfirstlane(__shfl(cv, j));
    float e[8];
#pragma unroll
    for (int j = 0; j < 8; j++) e[j] = aS[(sid[j] << 2) + head];
    ushort4 h[8];
#pragma unroll
    for (int j = 0; j < 8; j++) h[j] = *(const ushort4*)(h1b + ((size_t)sid[j] << 8) + c0);
    float wv[8];
#pragma unroll
    for (int j = 0; j < 8; j++) wv[j] = __expf(fminf(leaky(e[j] + ad), 80.f));
#pragma unroll
    for (int j = 0; j < 8; j++) {
      denom += wv[j];
      acc.x += wv[j] * bf2f(h[j].x);
      acc.y += wv[j] * bf2f(h[j].y);
      acc.z += wv[j] * bf2f(h[j].z);
      acc.w += wv[j] * bf2f(h[j].w);
    }
  }
  for (; i < s1; i++) {
    int s = __builtin_amdgcn_readfirstlane(col[i]);
    float e = aS[(s << 2) + head];
    ushort4 hv = *(const ushort4*)(h1b + ((size_t)s << 8) + c0);
    float wv = __expf(fminf(leaky(e + ad), 80.f));
    denom += wv;
    acc.x += wv * bf2f(hv.x);
    acc.y += wv * bf2f(hv.y);
    acc.z += wv * bf2f(hv.z);
    acc.w += wv * bf2f(hv.w);
  }
  float inv = 1.f / (denom + 1e-16f);
  float4 bb = *(const float4*)(b1 + c0);
  float4 gg = *(const float4*)(g1 + c0);
  float4 be = *(const float4*)(be1 + c0);
  float4 mm = *(const float4*)(m1 + c0);
  float4 vv = *(const float4*)(v1 + c0);
  ushort4 o;
  o.x = f2bf(elu_f((acc.x * inv + bb.x - mm.x) * rsqrtf(vv.x + BN_EPS) * gg.x + be.x));
  o.y = f2bf(elu_f((acc.y * inv + bb.y - mm.y) * rsqrtf(vv.y + BN_EPS) * gg.y + be.y));
  o.z = f2bf(elu_f((acc.z * inv + bb.z - mm.z) * rsqrtf(vv.z + BN_EPS) * gg.z + be.z));
  o.w = f2bf(elu_f((acc.w * inv + bb.w - mm.w) * rsqrtf(vv.w + BN_EPS) * gg.w + be.w));
  *(ushort4*)(hmb + (size_t)d * C1 + c0) = o;
}

// ---------------- GEMM2 (MFMA bf16): h2 = hm @ W2, fused att dots ----------------
__global__ void __launch_bounds__(256) k_gemm2(const unsigned short* __restrict__ hmb, const unsigned short* __restrict__ W2T,
                                               const float* __restrict__ attS, const float* __restrict__ attD,
                                               unsigned short* __restrict__ h2b, float* __restrict__ aS,
                                               float* __restrict__ aD) {
  __shared__ unsigned short As[64][C1 + 8];     // 33.8 KB
  int tid = threadIdx.x;
  int w = tid >> 6, lane = tid & 63;
  int l15 = lane & 15, l4 = lane >> 4;
  int row0 = blockIdx.x * 64;
#pragma unroll
  for (int it = 0; it < 8; it++) {
    int idx = tid + it * 256;          // uint4 chunk (8 bf16), 2048 total
    int r = idx >> 5;
    int k8 = (idx & 31) * 8;
    int gr = row0 + r; if (gr >= N_NODES) gr = N_NODES - 1;
    *(uint4*)&As[r][k8] = *(const uint4*)(hmb + (size_t)gr * C1 + k8);
  }
  __syncthreads();
  f32x4 acc[4];                        // [cf]
#pragma unroll
  for (int cf = 0; cf < 4; cf++) acc[cf] = (f32x4){0.f, 0.f, 0.f, 0.f};
#pragma unroll
  for (int ks = 0; ks < 8; ks++) {
    int koff = ks * 32 + l4 * 8;
    s16x8 a = *(const s16x8*)&As[w * 16 + l15][koff];
#pragma unroll
    for (int cf = 0; cf < 4; cf++) {
      s16x8 b = *(const s16x8*)(W2T + (size_t)(cf * 16 + l15) * C1 + koff);
      acc[cf] = MFMA16(a, b, acc[cf]);
    }
  }
  float as_c[4], ad_c[4];
#pragma unroll
  for (int cf = 0; cf < 4; cf++) {
    as_c[cf] = attS[cf * 16 + l15];
    ad_c[cf] = attD[cf * 16 + l15];
  }
#pragma unroll
  for (int reg = 0; reg < 4; reg++) {
    int gr = row0 + w * 16 + l4 * 4 + reg;
    bool ok = gr < N_NODES;
    float s = 0.f, dd = 0.f;
#pragma unroll
    for (int cf = 0; cf < 4; cf++) {
      float v = acc[cf][reg];
      if (ok) h2b[(size_t)gr * HID + cf * 16 + l15] = f2bf(v);
      s += v * as_c[cf];
      dd += v * ad_c[cf];
    }
#pragma unroll
    for (int m = 1; m <= 8; m <<= 1) { s += __shfl_xor(s, m, 64); dd += __shfl_xor(dd, m, 64); }
    if (ok && l15 == 0) { aS[gr] = s; aD[gr] = dd; }
  }
}

// ---------------- layer-2 aggregate: 8-deep pipelined gather, scalar bases ----------------
__global__ void __launch_bounds__(256) k_agg2(const int* __restrict__ row_ptr, const int* __restrict__ col,
                                              const float* __restrict__ aS, const float* __restrict__ aD,
                                              const unsigned short* __restrict__ h2b, const float* __restrict__ b2,
                                              const float* __restrict__ g2, const float* __restrict__ be2,
                                              const float* __restrict__ m2, const float* __restrict__ v2,
                                              float* __restrict__ emb) {
  int wave = threadIdx.x >> 6;
  int lane = threadIdx.x & 63;
  int d = blockIdx.x * 4 + wave;
  if (d >= N_NODES) return;
  float ad = aD[d];
  int s0 = row_ptr[d], s1 = row_ptr[d + 1];
  float denom = 0.f, acc = 0.f;
  int i = s0;
  int iend8 = s0 + ((s1 - s0) & ~7);
  for (; i < iend8; i += 8) {
    int cv = col[i + (lane & 7)];
    int sid[8];
#pragma unroll
    for (int j = 0; j < 8; j++) sid[j] = __builtin_amdgcn_readfirstlane(__shfl(cv, j));
    float e[8];
#pragma unroll
    for (int j = 0; j < 8; j++) e[j] = aS[sid[j]];
    unsigned short h[8];
#pragma unroll
    for (int j = 0; j < 8; j++) h[j] = h2b[((size_t)sid[j] << 6) + lane];
    float wv[8];
#pragma unroll
    for (int j = 0; j < 8; j++) wv[j] = __expf(fminf(leaky(e[j] + ad), 80.f));
#pragma unroll
    for (int j = 0; j < 8; j++) {
      denom += wv[j];
      acc += wv[j] * bf2f(h[j]);
    }
  }
  for (; i < s1; i++) {
    int s = __builtin_amdgcn_readfirstlane(col[i]);
    float e = aS[s];
    unsigned short hv = h2b[((size_t)s << 6) + lane];
    float wv = __expf(fminf(leaky(e + ad), 80.f));
    denom += wv;
    acc += wv * bf2f(hv);
  }
  float o = acc / (denom + 1e-16f) + b2[lane];
  o = (o - m2[lane]) * rsqrtf(v2[lane] + BN_EPS) * g2[lane] + be2[lane];
  emb[(size_t)d * HID + lane] = elu_f(o);
}

// ---------------- pooling partials ----------------
__global__ void __launch_bounds__(256) k_pool(const float* __restrict__ emb, float* __restrict__ psum,
                                              float* __restrict__ pmax) {
  __shared__ float ss[4][64], sm[4][64];
  int t = threadIdx.x;
  int c = t & 63, rg = t >> 6;
  float s = 0.f, m = -INFINITY;
  for (int n = blockIdx.x * 4 + rg; n < N_NODES; n += gridDim.x * 4) {
    float v = emb[(size_t)n * HID + c];
    s += v; m = fmaxf(m, v);
  }
  ss[rg][c] = s; sm[rg][c] = m;
  __syncthreads();
  if (t < 64) {
    psum[blockIdx.x * 64 + t] = ss[0][t] + ss[1][t] + ss[2][t] + ss[3][t];
    pmax[blockIdx.x * 64 + t] = fmaxf(fmaxf(sm[0][t], sm[1][t]), fmaxf(sm[2][t], sm[3][t]));
  }
}

// ---------------- final reduce + classifier ----------------
__global__ void __launch_bounds__(256) k_final(const float* __restrict__ psum, const float* __restrict__ pmax,
                                               const float* __restrict__ emb, const int* __restrict__ rootp,
                                               const float* __restrict__ cg1w, const float* __restrict__ cg1b,
                                               const float* __restrict__ cbng, const float* __restrict__ cbnb,
                                               const float* __restrict__ cbnm, const float* __restrict__ cbnv,
                                               const float* __restrict__ cg2w, const float* __restrict__ cg2b,
                                               const float* __restrict__ cg3w, const float* __restrict__ cg3b,
                                               float* __restrict__ out) {
  __shared__ float ss[4][64], sm[4][64];
  __shared__ float g[192], t1[64], t2[32];
  int t = threadIdx.x;
  int c = t & 63, q = t >> 6;
  float s = 0.f, m = -INFINITY;
  for (int b = q; b < 256; b += 4) {
    s += psum[b * 64 + c];
    m = fmaxf(m, pmax[b * 64 + c]);
  }
  ss[q][c] = s; sm[q][c] = m;
  __syncthreads();
  if (t < 64) {
    float tot = ss[0][t] + ss[1][t] + ss[2][t] + ss[3][t];
    float mx = fmaxf(fmaxf(sm[0][t], sm[1][t]), fmaxf(sm[2][t], sm[3][t]));
    int root = rootp[0];
    if (root > N_NODES - 1) root = N_NODES - 1;
    if (root < 0) root = 0;
    g[t] = tot / (float)N_NODES;
    g[64 + t] = mx;
    g[128 + t] = emb[(size_t)root * HID + t];
  }
  __syncthreads();
  if (t < 64) {
    float o = cg1b[t];
    for (int i = 0; i < 192; i++) o += g[i] * cg1w[i * 64 + t];
    o = (o - cbnm[t]) * rsqrtf(cbnv[t] + BN_EPS) * cbng[t] + cbnb[t];
    t1[t] = o > 0.f ? o : 0.f;
  }
  __syncthreads();
  if (t < 32) {
    float o = cg2b[t];
    for (int i = 0; i < 64; i++) o += t1[i] * cg2w[i * 32 + t];
    t2[t] = o > 0.f ? o : 0.f;
  }
  __syncthreads();
  if (t == 0) {
    float o = cg3b[0];
    for (int i = 0; i < 32; i++) o += t2[i] * cg3w[i];
    out[0] = o;
  }
}

extern "C" void kernel_launch(void* const* d_in, const int* in_sizes, int n_in,
                              void* d_out, int out_size, void* d_ws, size_t ws_size,
                              hipStream_t stream) {
  const float* x     = (const float*)d_in[0];
  const int*   edge  = (const int*)d_in[1];
  const int*   root  = (const int*)d_in[2];
  const float* W1    = (const float*)d_in[3];
  const float* attS1 = (const float*)d_in[4];
  const float* attD1 = (const float*)d_in[5];
  const float* b1    = (const float*)d_in[6];
  const float* W2    = (const float*)d_in[7];
  const float* attS2 = (const float*)d_in[8];
  const float* attD2 = (const float*)d_in[9];
  const float* b2    = (const float*)d_in[10];
  const float* bn1g  = (const float*)d_in[11];
  const float* bn1b  = (const float*)d_in[12];
  const float* bn1m  = (const float*)d_in[13];
  const float* bn1v  = (const float*)d_in[14];
  const float* bn2g  = (const float*)d_in[15];
  const float* bn2b  = (const float*)d_in[16];
  const float* bn2m  = (const float*)d_in[17];
  const float* bn2v  = (const float*)d_in[18];
  const float* cg1w  = (const float*)d_in[19];
  const float* cg1b  = (const float*)d_in[20];
  const float* cbng  = (const float*)d_in[21];
  const float* cbnb  = (const float*)d_in[22];
  const float* cbnm  = (const float*)d_in[23];
  const float* cbnv  = (const float*)d_in[24];
  const float* cg2w  = (const float*)d_in[25];
  const float* cg2b  = (const float*)d_in[26];
  const float* cg3w  = (const float*)d_in[27];
  const float* cg3b  = (const float*)d_in[28];

  // workspace arena (256B aligned blocks)
  char* ws = (char*)d_ws;
  size_t off = 0;
  auto carve = [&](size_t bytes) { char* p = ws + off; off += (bytes + 255) & ~(size_t)255; return p; };
  unsigned short* h1b = (unsigned short*)carve((size_t)N_NODES * C1 * 2);  // 51.2 MB
  unsigned short* hmb = (unsigned short*)carve((size_t)N_NODES * C1 * 2);  // 51.2 MB
  float* aS1     = (float*)carve((size_t)N_NODES * 4 * 4);
  float* aD1     = (float*)carve((size_t)N_NODES * 4 * 4);
  int*   deg     = (int*)  carve((size_t)N_NODES * 4);
  int*   row_ptr = (int*)  carve((size_t)(N_NODES + 1) * 4);
  int*   cursor  = (int*)  carve((size_t)N_NODES * 4);
  int*   col     = (int*)  carve((size_t)ETOT * 4);
  int*   part    = (int*)  carve(512);
  unsigned short* W1T = (unsigned short*)carve((size_t)IN_CH * C1 * 2);    // 64 KB
  unsigned short* W2T = (unsigned short*)carve((size_t)C1 * HID * 2);      // 32 KB
  // layer-2 buffers alias regions that are dead by the time they're written:
  unsigned short* h2b = h1b;                           // N*64 bf16 = 12.8 MB < 51.2
  float* aS2  = (float*)(h1b + (size_t)N_NODES * HID); // N
  float* aD2  = aS2 + N_NODES;
  float* emb  = (float*)hmb;                           // N*64 f32 = 25.6 MB < 51.2
  float* psum = emb + (size_t)N_NODES * HID;           // 256*64
  float* pmax = psum + 256 * 64;

  // CSR build + weight prep (deg/fill phased by dst range for L2 confinement)
  int bpp_deg  = (N_EDGES + 1023) >> 10;
  int bpp_fill = (ETOT + 255) >> 8;
  k_init_deg<<<(N_NODES + 255) / 256, 256, 0, stream>>>(deg);
  k_deg_ph<<<bpp_deg * FILL_PH, 256, 0, stream>>>(edge, deg);
  k_prep<<<(IN_CH * C1 + 255) / 256, 256, 0, stream>>>(W1, W2, W1T, W2T);
  k_scan_part<<<NCHUNK, 256, 0, stream>>>(deg, part);
  k_scan_top<<<1, 64, 0, stream>>>(part, row_ptr);
  k_scan_down<<<NCHUNK, 256, 0, stream>>>(deg, part, row_ptr, cursor);
  k_fill_ph<<<bpp_fill * FILL_PH, 256, 0, stream>>>(edge, cursor, col);
  // layer 1
  k_gemm1<<<(N_NODES + 63) / 64, 256, 0, stream>>>(x, W1T, attS1, attD1, h1b, aS1, aD1);
  k_agg1<<<(N_NODES + 3) / 4, 256, 0, stream>>>(row_ptr, col, aS1, aD1, h1b, b1, bn1g, bn1b, bn1m, bn1v, hmb);
  // layer 2
  k_gemm2<<<(N_NODES + 63) / 64, 256, 0, stream>>>(hmb, W2T, attS2, attD2, h2b, aS2, aD2);
  k_agg2<<<(N_NODES + 3) / 4, 256, 0, stream>>>(row_ptr, col, aS2, aD2, h2b, b2, bn2g, bn2b, bn2m, bn2v, emb);
  // pooling + classifier
  k_pool<<<256, 256, 0, stream>>>(emb, psum, pmax);
  k_final<<<1, 256, 0, stream>>>(psum, pmax, emb, root, cg1w, cg1b, cbng, cbnb, cbnm, cbnv,
                                 cg2w, cg2b, cg3w, cg3b, (float*)d_out);
}